// Round 7
// baseline (294.787 us; speedup 1.0000x reference)
//
#include <hip/hip_runtime.h>

#define N_NODES 50000
#define E_EDGES 1600000
#define HC 128
#define NEG_SLOPE 0.2f
#define SM_EPS 1e-16f
#define EPB 2048  // edges per k1 block

__device__ inline unsigned bf16pack(float a, float b) {
  unsigned ua = __float_as_uint(a), ub = __float_as_uint(b);
  ua = (ua + 0x7fffu + ((ua >> 16) & 1u)) >> 16;
  ub = (ub + 0x7fffu + ((ub >> 16) & 1u)) >> 16;
  return ua | (ub << 16);
}

// ---------------- K0: zero counts everywhere; block 0 also computes wvec ----------
__global__ __launch_bounds__(256) void k0_init(
    const float* __restrict__ v_mapping,  // [64,256]
    const float* __restrict__ att_src,    // [64]
    const float* __restrict__ att_dst,    // [64]
    float* __restrict__ wvec_src, float* __restrict__ wvec_dst,
    int* __restrict__ counts, int* __restrict__ gctr) {
  const int i = blockIdx.x * 256 + threadIdx.x;
  if (i < N_NODES) counts[i] = 0;
  if (blockIdx.x != 0) return;
  const int j = threadIdx.x;
  if (j == 0) *gctr = 0;
  float ns = 0.f, nd = 0.f;
  for (int f = 0; f < 64; ++f) {
    float a = att_src[f]; ns = fmaf(a, a, ns);
    float b = att_dst[f]; nd = fmaf(b, b, nd);
  }
  ns = fmaxf(sqrtf(ns), 1e-12f);
  nd = fmaxf(sqrtf(nd), 1e-12f);
  float ws_ = 0.f, wd_ = 0.f;
  for (int f = 0; f < 64; ++f) {
    float v = v_mapping[f * 256 + j];
    ws_ = fmaf(v, att_src[f], ws_);
    wd_ = fmaf(v, att_dst[f], wd_);
  }
  wvec_src[j] = ws_ / ns;
  wvec_dst[j] = wd_ / nd;
}

// ---------------- K1: node GEMM + dots, fused with edge histogram/rank ----------
// block: 64 rows x 128 cols; thread (ty,tx): rows ty*8..+7, cols tx*4..+3
// plus: block owns edges [blockIdx*2048, +2048): histogram atomics + rank write.
__global__ __launch_bounds__(256) void k1_node(
    const float* __restrict__ x,      // [N,256]
    const float* __restrict__ W,      // [256,128]
    const float* __restrict__ wvec_src, const float* __restrict__ wvec_dst,
    unsigned* __restrict__ xpb,       // [N,64]  bf16x2 packed
    float* __restrict__ a_src, float* __restrict__ a_dst,
    const int* __restrict__ ei,
    int* __restrict__ counts, int* __restrict__ rank) {
  __shared__ float xs[64][68];
  const int tid = threadIdx.x;
  const int rowbase = blockIdx.x * 64;
  const int ty = tid >> 5, tx = tid & 31;

  // edge dst loads (coalesced, independent) — consumed by atomics later
  const int ebase = blockIdx.x * EPB;
  int dvals[8];
#pragma unroll
  for (int i = 0; i < 8; ++i) {
    const int e = ebase + i * 256 + tid;
    dvals[i] = (e < E_EDGES) ? ei[E_EDGES + e] : -1;
  }

  float acc[8][4];
#pragma unroll
  for (int i = 0; i < 8; ++i)
#pragma unroll
    for (int j = 0; j < 4; ++j) acc[i][j] = 0.f;

  float dot_part = 0.f;
  const int dl = tid & 127;
  const int drow = dl >> 1;
  const int dkh = (dl & 1) * 32;
  const float* wv = (tid < 128) ? wvec_src : wvec_dst;

  const float4* W4 = (const float4*)W;
  const float4* x4 = (const float4*)x;

  for (int chunk = 0; chunk < 4; ++chunk) {
    const int cb16 = chunk * 16;
#pragma unroll
    for (int p = 0; p < 4; ++p) {
      const int row = (tid >> 4) + p * 16;
      const int k4 = tid & 15;
      float4 v = make_float4(0.f, 0.f, 0.f, 0.f);
      if (rowbase + row < N_NODES) v = x4[(size_t)(rowbase + row) * 64 + cb16 + k4];
      *(float4*)&xs[row][k4 * 4] = v;
    }
    __syncthreads();

#pragma unroll 4
    for (int k = 0; k < 64; ++k) {
      const float4 w4 = W4[(size_t)(chunk * 64 + k) * 32 + tx];
      float xv[8];
#pragma unroll
      for (int i = 0; i < 8; ++i) xv[i] = xs[ty * 8 + i][k];
#pragma unroll
      for (int i = 0; i < 8; ++i) {
        acc[i][0] = fmaf(xv[i], w4.x, acc[i][0]);
        acc[i][1] = fmaf(xv[i], w4.y, acc[i][1]);
        acc[i][2] = fmaf(xv[i], w4.z, acc[i][2]);
        acc[i][3] = fmaf(xv[i], w4.w, acc[i][3]);
      }
    }

#pragma unroll 8
    for (int j = 0; j < 32; ++j)
      dot_part = fmaf(xs[drow][dkh + j], wv[chunk * 64 + dkh + j], dot_part);
    __syncthreads();
  }

  // issue histogram atomics; returns land while epilogue runs + other waves compute
  int rnk[8];
#pragma unroll
  for (int i = 0; i < 8; ++i)
    if (dvals[i] >= 0) rnk[i] = atomicAdd(&counts[dvals[i]], 1);

  {
    float tot = dot_part + __shfl_xor(dot_part, 1);
    const int row = rowbase + drow;
    if ((dl & 1) == 0 && row < N_NODES) {
      if (tid < 128) a_src[row] = tot;
      else a_dst[row] = tot;
    }
  }

#pragma unroll
  for (int i = 0; i < 8; ++i) {
    const int row = rowbase + ty * 8 + i;
    if (row < N_NODES) {
      uint2 p;
      p.x = bf16pack(acc[i][0], acc[i][1]);
      p.y = bf16pack(acc[i][2], acc[i][3]);
      ((uint2*)(xpb + (size_t)row * 64))[tx] = p;
    }
  }

#pragma unroll
  for (int i = 0; i < 8; ++i) {
    const int e = ebase + i * 256 + tid;
    if (e < E_EDGES) rank[e] = rnk[i];
  }
}

// ---------------- KR: range assign (block scan + one global atomic) ----------------
__global__ __launch_bounds__(256) void kr_range(const int* __restrict__ counts,
                                                int* __restrict__ row_start,
                                                int* __restrict__ gctr) {
  __shared__ int woff[4];
  __shared__ int s_base;
  const int i = blockIdx.x * 256 + threadIdx.x;
  const int lane = threadIdx.x & 63, w = threadIdx.x >> 6;
  const int c = (i < N_NODES) ? counts[i] : 0;
  int inc = c;
#pragma unroll
  for (int off = 1; off < 64; off <<= 1) {
    int t = __shfl_up(inc, off);
    if (lane >= off) inc += t;
  }
  if (lane == 63) woff[w] = inc;
  __syncthreads();
  if (threadIdx.x == 0) {
    int s = 0;
#pragma unroll
    for (int k = 0; k < 4; ++k) { int t = woff[k]; woff[k] = s; s += t; }
    s_base = atomicAdd(gctr, s);
  }
  __syncthreads();
  if (i < N_NODES) row_start[i] = s_base + woff[w] + inc - c;
}

// ---------------- KD: compute ev, permutation scatter of (src, ev), atomic-free ----
__global__ __launch_bounds__(256) void kd_scatter(
    const int* __restrict__ ei,
    const float* __restrict__ a_src, const float* __restrict__ a_dst,
    const int* __restrict__ row_start, const int* __restrict__ rank,
    int2* __restrict__ sorted) {
  int e = blockIdx.x * 256 + threadIdx.x;
  int s = ei[e];
  int d = ei[E_EDGES + e];
  float a = a_src[s] + a_dst[d];
  a = a > 0.f ? a : NEG_SLOPE * a;
  const float ev = __expf(a);
  sorted[row_start[d] + rank[e]] = make_int2(s, __float_as_int(ev));
}

// ---------------- KE: per-dst gather-reduce, 16 lanes/dst, uint4 gather ----------
__global__ __launch_bounds__(256) void ke_reduce(
    const int* __restrict__ row_start, const int* __restrict__ counts,
    const int2* __restrict__ sorted,
    const unsigned* __restrict__ xpb,   // [N,64] bf16x2
    const float* __restrict__ bias,     // [128]
    float* __restrict__ out) {
  const int tid = threadIdx.x;
  const int w = tid >> 6;
  const int lane = tid & 63;
  const int g = lane >> 4;
  const int gl = lane & 15;
  const int dst = blockIdx.x * 16 + w * 4 + g;
  const int start = row_start[dst];
  const int cnt = counts[dst];

  float acc[8];
#pragma unroll
  for (int i = 0; i < 8; ++i) acc[i] = 0.f;
  float den = 0.f;

  const int2* sp = sorted + start;
  const uint4* xp4 = (const uint4*)xpb;

  if (cnt > 0) {
    int2 se = sp[0];
    for (int j = 0; j + 1 < cnt; ++j) {
      const int2 sn = sp[j + 1];
      const uint4 u = xp4[(size_t)se.x * 16 + gl];
      const float ev = __int_as_float(se.y);
      den += ev;
      acc[0] = fmaf(ev, __uint_as_float(u.x << 16), acc[0]);
      acc[1] = fmaf(ev, __uint_as_float(u.x & 0xffff0000u), acc[1]);
      acc[2] = fmaf(ev, __uint_as_float(u.y << 16), acc[2]);
      acc[3] = fmaf(ev, __uint_as_float(u.y & 0xffff0000u), acc[3]);
      acc[4] = fmaf(ev, __uint_as_float(u.z << 16), acc[4]);
      acc[5] = fmaf(ev, __uint_as_float(u.z & 0xffff0000u), acc[5]);
      acc[6] = fmaf(ev, __uint_as_float(u.w << 16), acc[6]);
      acc[7] = fmaf(ev, __uint_as_float(u.w & 0xffff0000u), acc[7]);
      se = sn;
    }
    {
      const uint4 u = xp4[(size_t)se.x * 16 + gl];
      const float ev = __int_as_float(se.y);
      den += ev;
      acc[0] = fmaf(ev, __uint_as_float(u.x << 16), acc[0]);
      acc[1] = fmaf(ev, __uint_as_float(u.x & 0xffff0000u), acc[1]);
      acc[2] = fmaf(ev, __uint_as_float(u.y << 16), acc[2]);
      acc[3] = fmaf(ev, __uint_as_float(u.y & 0xffff0000u), acc[3]);
      acc[4] = fmaf(ev, __uint_as_float(u.z << 16), acc[4]);
      acc[5] = fmaf(ev, __uint_as_float(u.z & 0xffff0000u), acc[5]);
      acc[6] = fmaf(ev, __uint_as_float(u.w << 16), acc[6]);
      acc[7] = fmaf(ev, __uint_as_float(u.w & 0xffff0000u), acc[7]);
    }
  }

  const float inv = 1.f / (den + SM_EPS);
  // residual from bf16 xpb + bias + agg
  const uint4 ur = xp4[(size_t)dst * 16 + gl];
  const float4* br = (const float4*)bias;
  const float4 b0 = br[2 * gl], b1 = br[2 * gl + 1];
  float4 o0, o1;
  o0.x = __uint_as_float(ur.x << 16)          + b0.x + acc[0] * inv;
  o0.y = __uint_as_float(ur.x & 0xffff0000u)  + b0.y + acc[1] * inv;
  o0.z = __uint_as_float(ur.y << 16)          + b0.z + acc[2] * inv;
  o0.w = __uint_as_float(ur.y & 0xffff0000u)  + b0.w + acc[3] * inv;
  o1.x = __uint_as_float(ur.z << 16)          + b1.x + acc[4] * inv;
  o1.y = __uint_as_float(ur.z & 0xffff0000u)  + b1.y + acc[5] * inv;
  o1.z = __uint_as_float(ur.w << 16)          + b1.z + acc[6] * inv;
  o1.w = __uint_as_float(ur.w & 0xffff0000u)  + b1.w + acc[7] * inv;
  float4* orow = (float4*)(out + (size_t)dst * HC);
  orow[2 * gl] = o0;
  orow[2 * gl + 1] = o1;
}

extern "C" void kernel_launch(void* const* d_in, const int* in_sizes, int n_in,
                              void* d_out, int out_size, void* d_ws, size_t ws_size,
                              hipStream_t stream) {
  const float* x         = (const float*)d_in[0];
  const int*   ei        = (const int*)d_in[1];
  const float* v_mapping = (const float*)d_in[2];
  const float* W_src     = (const float*)d_in[3];
  const float* att_src   = (const float*)d_in[4];
  const float* att_dst   = (const float*)d_in[5];
  const float* bias      = (const float*)d_in[6];
  float* out = (float*)d_out;

  char* ws = (char*)d_ws;
  unsigned* xpb        = (unsigned*)ws;  ws += (size_t)N_NODES * 64 * 4;  // 12.8 MB
  float*    a_src      = (float*)ws;     ws += (size_t)N_NODES * 4;
  float*    a_dst      = (float*)ws;     ws += (size_t)N_NODES * 4;
  float*    wvec_src   = (float*)ws;     ws += 256 * 4;
  float*    wvec_dst   = (float*)ws;     ws += 256 * 4;
  int*      counts     = (int*)ws;       ws += (size_t)N_NODES * 4;
  int*      row_start  = (int*)ws;       ws += (size_t)N_NODES * 4;
  int*      gctr       = (int*)ws;       ws += 256;
  int*      rank       = (int*)ws;       ws += (size_t)E_EDGES * 4;       // 6.4 MB
  int2*     sorted     = (int2*)ws;      ws += (size_t)E_EDGES * 8;       // 12.8 MB

  k0_init<<<(N_NODES + 255) / 256, 256, 0, stream>>>(v_mapping, att_src, att_dst,
                                                     wvec_src, wvec_dst, counts, gctr);
  k1_node<<<(N_NODES + 63) / 64, 256, 0, stream>>>(x, W_src, wvec_src, wvec_dst,
                                                   xpb, a_src, a_dst, ei, counts, rank);
  kr_range<<<(N_NODES + 255) / 256, 256, 0, stream>>>(counts, row_start, gctr);
  kd_scatter<<<E_EDGES / 256, 256, 0, stream>>>(ei, a_src, a_dst, row_start, rank, sorted);
  ke_reduce<<<N_NODES / 16, 256, 0, stream>>>(row_start, counts, sorted,
                                              xpb, bias, out);
}

// Round 8
// 249.191 us; speedup vs baseline: 1.1830x; 1.1830x over previous
//
#include <hip/hip_runtime.h>

#define N_NODES 50000
#define E_EDGES 1600000
#define HC 128
#define NEG_SLOPE 0.2f
#define SM_EPS 1e-16f

__device__ inline unsigned bf16pack(float a, float b) {
  unsigned ua = __float_as_uint(a), ub = __float_as_uint(b);
  ua = (ua + 0x7fffu + ((ua >> 16) & 1u)) >> 16;
  ub = (ub + 0x7fffu + ((ub >> 16) & 1u)) >> 16;
  return ua | (ub << 16);
}

// ---------------- K0: wvec = v_mapping.T @ l2norm(att); zero gctr ----------------
__global__ __launch_bounds__(256) void k0_wvec(
    const float* __restrict__ v_mapping,  // [64,256]
    const float* __restrict__ att_src,    // [64]
    const float* __restrict__ att_dst,    // [64]
    float* __restrict__ wvec_src, float* __restrict__ wvec_dst,
    int* __restrict__ gctr) {
  int j = threadIdx.x;  // 0..255
  if (j == 0) *gctr = 0;
  float ns = 0.f, nd = 0.f;
  for (int f = 0; f < 64; ++f) {
    float a = att_src[f]; ns = fmaf(a, a, ns);
    float b = att_dst[f]; nd = fmaf(b, b, nd);
  }
  ns = fmaxf(sqrtf(ns), 1e-12f);
  nd = fmaxf(sqrtf(nd), 1e-12f);
  float ws_ = 0.f, wd_ = 0.f;
  for (int f = 0; f < 64; ++f) {
    float v = v_mapping[f * 256 + j];
    ws_ = fmaf(v, att_src[f], ws_);
    wd_ = fmaf(v, att_dst[f], wd_);
  }
  wvec_src[j] = ws_ / ns;
  wvec_dst[j] = wd_ / nd;
}

// ---------------- K1: node phase (register-tiled GEMM + dots) ----------------
// block: 64 rows x 128 cols; thread (ty=tid>>5, tx=tid&31): rows ty*8..+7, cols tx*4..+3
__global__ __launch_bounds__(256) void k1_node(
    const float* __restrict__ x,      // [N,256]
    const float* __restrict__ W,      // [256,128]
    const float* __restrict__ wvec_src, const float* __restrict__ wvec_dst,
    unsigned* __restrict__ xpb,       // [N,64]  bf16x2 packed
    float* __restrict__ a_src, float* __restrict__ a_dst,
    int* __restrict__ counts) {
  __shared__ float xs[64][68];  // 64 rows x 64-k chunk, padded (row stride 272B, 16B-aligned)
  const int tid = threadIdx.x;
  const int rowbase = blockIdx.x * 64;
  const int ty = tid >> 5, tx = tid & 31;

  if (tid < 64) {
    int idx = rowbase + tid;
    if (idx < N_NODES) counts[idx] = 0;
  }

  float acc[8][4];
#pragma unroll
  for (int i = 0; i < 8; ++i)
#pragma unroll
    for (int j = 0; j < 4; ++j) acc[i][j] = 0.f;

  float dot_part = 0.f;  // waves 0-1: a_src partial; waves 2-3: a_dst partial
  const int dl = tid & 127;
  const int drow = dl >> 1;
  const int dkh = (dl & 1) * 32;
  const float* wv = (tid < 128) ? wvec_src : wvec_dst;

  const float4* W4 = (const float4*)W;
  const float4* x4 = (const float4*)x;

  for (int chunk = 0; chunk < 4; ++chunk) {
    const int cb16 = chunk * 16;
#pragma unroll
    for (int p = 0; p < 4; ++p) {
      const int row = (tid >> 4) + p * 16;
      const int k4 = tid & 15;
      float4 v = make_float4(0.f, 0.f, 0.f, 0.f);
      if (rowbase + row < N_NODES) v = x4[(size_t)(rowbase + row) * 64 + cb16 + k4];
      *(float4*)&xs[row][k4 * 4] = v;
    }
    __syncthreads();

    // k-step-4 inner loop: 4 W float4 loads + 8 LDS b128 reads + 128 FMAs per group
#pragma unroll 2
    for (int kk = 0; kk < 64; kk += 4) {
      const float4 wa = W4[(size_t)(chunk * 64 + kk + 0) * 32 + tx];
      const float4 wb = W4[(size_t)(chunk * 64 + kk + 1) * 32 + tx];
      const float4 wc = W4[(size_t)(chunk * 64 + kk + 2) * 32 + tx];
      const float4 wd = W4[(size_t)(chunk * 64 + kk + 3) * 32 + tx];
#pragma unroll
      for (int i = 0; i < 8; ++i) {
        const float4 xv = *(const float4*)&xs[ty * 8 + i][kk];
        acc[i][0] = fmaf(xv.x, wa.x, acc[i][0]);
        acc[i][1] = fmaf(xv.x, wa.y, acc[i][1]);
        acc[i][2] = fmaf(xv.x, wa.z, acc[i][2]);
        acc[i][3] = fmaf(xv.x, wa.w, acc[i][3]);
        acc[i][0] = fmaf(xv.y, wb.x, acc[i][0]);
        acc[i][1] = fmaf(xv.y, wb.y, acc[i][1]);
        acc[i][2] = fmaf(xv.y, wb.z, acc[i][2]);
        acc[i][3] = fmaf(xv.y, wb.w, acc[i][3]);
        acc[i][0] = fmaf(xv.z, wc.x, acc[i][0]);
        acc[i][1] = fmaf(xv.z, wc.y, acc[i][1]);
        acc[i][2] = fmaf(xv.z, wc.z, acc[i][2]);
        acc[i][3] = fmaf(xv.z, wc.w, acc[i][3]);
        acc[i][0] = fmaf(xv.w, wd.x, acc[i][0]);
        acc[i][1] = fmaf(xv.w, wd.y, acc[i][1]);
        acc[i][2] = fmaf(xv.w, wd.z, acc[i][2]);
        acc[i][3] = fmaf(xv.w, wd.w, acc[i][3]);
      }
    }

#pragma unroll 8
    for (int j = 0; j < 32; ++j)
      dot_part = fmaf(xs[drow][dkh + j], wv[chunk * 64 + dkh + j], dot_part);
    __syncthreads();
  }

  {
    float tot = dot_part + __shfl_xor(dot_part, 1);
    const int row = rowbase + drow;
    if ((dl & 1) == 0 && row < N_NODES) {
      if (tid < 128) a_src[row] = tot;
      else a_dst[row] = tot;
    }
  }

#pragma unroll
  for (int i = 0; i < 8; ++i) {
    const int row = rowbase + ty * 8 + i;
    if (row < N_NODES) {
      uint2 p;
      p.x = bf16pack(acc[i][0], acc[i][1]);
      p.y = bf16pack(acc[i][2], acc[i][3]);
      ((uint2*)(xpb + (size_t)row * 64))[tx] = p;
    }
  }
}

// ---------------- KB: dst histogram + per-edge rank (4 edges/thread) ----------------
__global__ __launch_bounds__(256) void kb_hist(const int* __restrict__ ei,
                                               int* __restrict__ counts,
                                               int* __restrict__ rank) {
  const int t = blockIdx.x * 256 + threadIdx.x;
  if (t >= E_EDGES / 4) return;
  const int4 d4 = ((const int4*)(ei + E_EDGES))[t];
  int4 r;
  r.x = atomicAdd(&counts[d4.x], 1);
  r.y = atomicAdd(&counts[d4.y], 1);
  r.z = atomicAdd(&counts[d4.z], 1);
  r.w = atomicAdd(&counts[d4.w], 1);
  ((int4*)rank)[t] = r;
}

// ---------------- KR: range assign (block scan + one global atomic) ----------------
__global__ __launch_bounds__(256) void kr_range(const int* __restrict__ counts,
                                                int* __restrict__ row_start,
                                                int* __restrict__ gctr) {
  __shared__ int woff[4];
  __shared__ int s_base;
  const int i = blockIdx.x * 256 + threadIdx.x;
  const int lane = threadIdx.x & 63, w = threadIdx.x >> 6;
  const int c = (i < N_NODES) ? counts[i] : 0;
  int inc = c;
#pragma unroll
  for (int off = 1; off < 64; off <<= 1) {
    int t = __shfl_up(inc, off);
    if (lane >= off) inc += t;
  }
  if (lane == 63) woff[w] = inc;
  __syncthreads();
  if (threadIdx.x == 0) {
    int s = 0;
#pragma unroll
    for (int k = 0; k < 4; ++k) { int t = woff[k]; woff[k] = s; s += t; }
    s_base = atomicAdd(gctr, s);
  }
  __syncthreads();
  if (i < N_NODES) row_start[i] = s_base + woff[w] + inc - c;
}

// ---------------- KD: compute ev, permutation scatter of (src, ev), atomic-free ----
__global__ __launch_bounds__(256) void kd_scatter(
    const int* __restrict__ ei,
    const float* __restrict__ a_src, const float* __restrict__ a_dst,
    const int* __restrict__ row_start, const int* __restrict__ rank,
    int2* __restrict__ sorted) {
  int e = blockIdx.x * 256 + threadIdx.x;
  int s = ei[e];
  int d = ei[E_EDGES + e];
  float a = a_src[s] + a_dst[d];
  a = a > 0.f ? a : NEG_SLOPE * a;
  const float ev = __expf(a);
  sorted[row_start[d] + rank[e]] = make_int2(s, __float_as_int(ev));
}

// ---------------- KE: per-dst gather-reduce, 16 lanes/dst, uint4 gather ----------
__global__ __launch_bounds__(256) void ke_reduce(
    const int* __restrict__ row_start, const int* __restrict__ counts,
    const int2* __restrict__ sorted,
    const unsigned* __restrict__ xpb,   // [N,64] bf16x2
    const float* __restrict__ bias,     // [128]
    float* __restrict__ out) {
  const int tid = threadIdx.x;
  const int w = tid >> 6;
  const int lane = tid & 63;
  const int g = lane >> 4;
  const int gl = lane & 15;
  const int dst = blockIdx.x * 16 + w * 4 + g;
  const int start = row_start[dst];
  const int cnt = counts[dst];

  float acc[8];
#pragma unroll
  for (int i = 0; i < 8; ++i) acc[i] = 0.f;
  float den = 0.f;

  const int2* sp = sorted + start;
  const uint4* xp4 = (const uint4*)xpb;

  if (cnt > 0) {
    int2 se = sp[0];
    for (int j = 0; j + 1 < cnt; ++j) {
      const int2 sn = sp[j + 1];
      const uint4 u = xp4[(size_t)se.x * 16 + gl];
      const float ev = __int_as_float(se.y);
      den += ev;
      acc[0] = fmaf(ev, __uint_as_float(u.x << 16), acc[0]);
      acc[1] = fmaf(ev, __uint_as_float(u.x & 0xffff0000u), acc[1]);
      acc[2] = fmaf(ev, __uint_as_float(u.y << 16), acc[2]);
      acc[3] = fmaf(ev, __uint_as_float(u.y & 0xffff0000u), acc[3]);
      acc[4] = fmaf(ev, __uint_as_float(u.z << 16), acc[4]);
      acc[5] = fmaf(ev, __uint_as_float(u.z & 0xffff0000u), acc[5]);
      acc[6] = fmaf(ev, __uint_as_float(u.w << 16), acc[6]);
      acc[7] = fmaf(ev, __uint_as_float(u.w & 0xffff0000u), acc[7]);
      se = sn;
    }
    {
      const uint4 u = xp4[(size_t)se.x * 16 + gl];
      const float ev = __int_as_float(se.y);
      den += ev;
      acc[0] = fmaf(ev, __uint_as_float(u.x << 16), acc[0]);
      acc[1] = fmaf(ev, __uint_as_float(u.x & 0xffff0000u), acc[1]);
      acc[2] = fmaf(ev, __uint_as_float(u.y << 16), acc[2]);
      acc[3] = fmaf(ev, __uint_as_float(u.y & 0xffff0000u), acc[3]);
      acc[4] = fmaf(ev, __uint_as_float(u.z << 16), acc[4]);
      acc[5] = fmaf(ev, __uint_as_float(u.z & 0xffff0000u), acc[5]);
      acc[6] = fmaf(ev, __uint_as_float(u.w << 16), acc[6]);
      acc[7] = fmaf(ev, __uint_as_float(u.w & 0xffff0000u), acc[7]);
    }
  }

  const float inv = 1.f / (den + SM_EPS);
  const uint4 ur = xp4[(size_t)dst * 16 + gl];
  const float4* br = (const float4*)bias;
  const float4 b0 = br[2 * gl], b1 = br[2 * gl + 1];
  float4 o0, o1;
  o0.x = __uint_as_float(ur.x << 16)          + b0.x + acc[0] * inv;
  o0.y = __uint_as_float(ur.x & 0xffff0000u)  + b0.y + acc[1] * inv;
  o0.z = __uint_as_float(ur.y << 16)          + b0.z + acc[2] * inv;
  o0.w = __uint_as_float(ur.y & 0xffff0000u)  + b0.w + acc[3] * inv;
  o1.x = __uint_as_float(ur.z << 16)          + b1.x + acc[4] * inv;
  o1.y = __uint_as_float(ur.z & 0xffff0000u)  + b1.y + acc[5] * inv;
  o1.z = __uint_as_float(ur.w << 16)          + b1.z + acc[6] * inv;
  o1.w = __uint_as_float(ur.w & 0xffff0000u)  + b1.w + acc[7] * inv;
  float4* orow = (float4*)(out + (size_t)dst * HC);
  orow[2 * gl] = o0;
  orow[2 * gl + 1] = o1;
}

extern "C" void kernel_launch(void* const* d_in, const int* in_sizes, int n_in,
                              void* d_out, int out_size, void* d_ws, size_t ws_size,
                              hipStream_t stream) {
  const float* x         = (const float*)d_in[0];
  const int*   ei        = (const int*)d_in[1];
  const float* v_mapping = (const float*)d_in[2];
  const float* W_src     = (const float*)d_in[3];
  const float* att_src   = (const float*)d_in[4];
  const float* att_dst   = (const float*)d_in[5];
  const float* bias      = (const float*)d_in[6];
  float* out = (float*)d_out;

  char* ws = (char*)d_ws;
  unsigned* xpb        = (unsigned*)ws;  ws += (size_t)N_NODES * 64 * 4;  // 12.8 MB
  float*    a_src      = (float*)ws;     ws += (size_t)N_NODES * 4;
  float*    a_dst      = (float*)ws;     ws += (size_t)N_NODES * 4;
  float*    wvec_src   = (float*)ws;     ws += 256 * 4;
  float*    wvec_dst   = (float*)ws;     ws += 256 * 4;
  int*      counts     = (int*)ws;       ws += (size_t)N_NODES * 4;
  int*      row_start  = (int*)ws;       ws += (size_t)N_NODES * 4;
  int*      gctr       = (int*)ws;       ws += 256;
  int*      rank       = (int*)ws;       ws += (size_t)E_EDGES * 4;       // 6.4 MB
  int2*     sorted     = (int2*)ws;      ws += (size_t)E_EDGES * 8;       // 12.8 MB

  k0_wvec<<<1, 256, 0, stream>>>(v_mapping, att_src, att_dst, wvec_src, wvec_dst, gctr);
  k1_node<<<(N_NODES + 63) / 64, 256, 0, stream>>>(x, W_src, wvec_src, wvec_dst,
                                                   xpb, a_src, a_dst, counts);
  kb_hist<<<(E_EDGES / 4 + 255) / 256, 256, 0, stream>>>(ei, counts, rank);
  kr_range<<<(N_NODES + 255) / 256, 256, 0, stream>>>(counts, row_start, gctr);
  kd_scatter<<<E_EDGES / 256, 256, 0, stream>>>(ei, a_src, a_dst, row_start, rank, sorted);
  ke_reduce<<<N_NODES / 16, 256, 0, stream>>>(row_start, counts, sorted,
                                              xpb, bias, out);
}

// Round 9
// 217.394 us; speedup vs baseline: 1.3560x; 1.1463x over previous
//
#include <hip/hip_runtime.h>

#define N_NODES 50000
#define E_EDGES 1600000
#define HC 128
#define NEG_SLOPE 0.2f
#define SM_EPS 1e-16f
#define NB_GEMM 782   // ceil(50000/64)
#define NB_HIST 782   // 2048 edges each

__device__ inline unsigned bf16pack(float a, float b) {
  unsigned ua = __float_as_uint(a), ub = __float_as_uint(b);
  ua = (ua + 0x7fffu + ((ua >> 16) & 1u)) >> 16;
  ub = (ub + 0x7fffu + ((ub >> 16) & 1u)) >> 16;
  return ua | (ub << 16);
}

// ---------------- K0: zero counts; block 0 computes wvec + zeroes gctr ----------
__global__ __launch_bounds__(256) void k0_init(
    const float* __restrict__ v_mapping,  // [64,256]
    const float* __restrict__ att_src,    // [64]
    const float* __restrict__ att_dst,    // [64]
    float* __restrict__ wvec_src, float* __restrict__ wvec_dst,
    int* __restrict__ counts, int* __restrict__ gctr) {
  const int i = blockIdx.x * 256 + threadIdx.x;
  if (i < N_NODES) counts[i] = 0;
  if (blockIdx.x != 0) return;
  const int j = threadIdx.x;
  if (j == 0) *gctr = 0;
  float ns = 0.f, nd = 0.f;
  for (int f = 0; f < 64; ++f) {
    float a = att_src[f]; ns = fmaf(a, a, ns);
    float b = att_dst[f]; nd = fmaf(b, b, nd);
  }
  ns = fmaxf(sqrtf(ns), 1e-12f);
  nd = fmaxf(sqrtf(nd), 1e-12f);
  float ws_ = 0.f, wd_ = 0.f;
  for (int f = 0; f < 64; ++f) {
    float v = v_mapping[f * 256 + j];
    ws_ = fmaf(v, att_src[f], ws_);
    wd_ = fmaf(v, att_dst[f], wd_);
  }
  wvec_src[j] = ws_ / ns;
  wvec_dst[j] = wd_ / nd;
}

// ---------------- K1: block-role fused — even: GEMM+dots, odd: histogram ----------
__global__ __launch_bounds__(256) void k1_fused(
    const float* __restrict__ x,      // [N,256]
    const float* __restrict__ W,      // [256,128]
    const float* __restrict__ wvec_src, const float* __restrict__ wvec_dst,
    unsigned* __restrict__ xpb,       // [N,64]  bf16x2 packed
    float* __restrict__ a_src, float* __restrict__ a_dst,
    const int* __restrict__ ei,
    int* __restrict__ counts, int* __restrict__ rank) {
  const int bid = blockIdx.x;
  const int tid = threadIdx.x;

  if (bid & 1) {
    // -------- histogram role: 2048 edges, latency-bound, hides under GEMM blocks
    const int hb = bid >> 1;
    const int i40 = hb * 512 + tid;     // int4 index (4 edges)
    const int i41 = i40 + 256;
    const int4* d4p = (const int4*)(ei + E_EDGES);
    const bool v0 = i40 < E_EDGES / 4;
    const bool v1 = i41 < E_EDGES / 4;
    int4 r0, r1;
    if (v0) {
      const int4 d = d4p[i40];
      r0.x = atomicAdd(&counts[d.x], 1);
      r0.y = atomicAdd(&counts[d.y], 1);
      r0.z = atomicAdd(&counts[d.z], 1);
      r0.w = atomicAdd(&counts[d.w], 1);
    }
    if (v1) {
      const int4 d = d4p[i41];
      r1.x = atomicAdd(&counts[d.x], 1);
      r1.y = atomicAdd(&counts[d.y], 1);
      r1.z = atomicAdd(&counts[d.z], 1);
      r1.w = atomicAdd(&counts[d.w], 1);
    }
    if (v0) ((int4*)rank)[i40] = r0;
    if (v1) ((int4*)rank)[i41] = r1;
    return;
  }

  // -------- GEMM role (R6 structure)
  __shared__ float xs[64][68];
  const int rowbase = (bid >> 1) * 64;
  const int ty = tid >> 5, tx = tid & 31;

  float acc[8][4];
#pragma unroll
  for (int i = 0; i < 8; ++i)
#pragma unroll
    for (int j = 0; j < 4; ++j) acc[i][j] = 0.f;

  float dot_part = 0.f;
  const int dl = tid & 127;
  const int drow = dl >> 1;
  const int dkh = (dl & 1) * 32;
  const float* wv = (tid < 128) ? wvec_src : wvec_dst;

  const float4* W4 = (const float4*)W;
  const float4* x4 = (const float4*)x;

  for (int chunk = 0; chunk < 4; ++chunk) {
    const int cb16 = chunk * 16;
#pragma unroll
    for (int p = 0; p < 4; ++p) {
      const int row = (tid >> 4) + p * 16;
      const int k4 = tid & 15;
      float4 v = make_float4(0.f, 0.f, 0.f, 0.f);
      if (rowbase + row < N_NODES) v = x4[(size_t)(rowbase + row) * 64 + cb16 + k4];
      *(float4*)&xs[row][k4 * 4] = v;
    }
    __syncthreads();

#pragma unroll 4
    for (int k = 0; k < 64; ++k) {
      const float4 w4 = W4[(size_t)(chunk * 64 + k) * 32 + tx];
      float xv[8];
#pragma unroll
      for (int i = 0; i < 8; ++i) xv[i] = xs[ty * 8 + i][k];
#pragma unroll
      for (int i = 0; i < 8; ++i) {
        acc[i][0] = fmaf(xv[i], w4.x, acc[i][0]);
        acc[i][1] = fmaf(xv[i], w4.y, acc[i][1]);
        acc[i][2] = fmaf(xv[i], w4.z, acc[i][2]);
        acc[i][3] = fmaf(xv[i], w4.w, acc[i][3]);
      }
    }

#pragma unroll 8
    for (int j = 0; j < 32; ++j)
      dot_part = fmaf(xs[drow][dkh + j], wv[chunk * 64 + dkh + j], dot_part);
    __syncthreads();
  }

  {
    float tot = dot_part + __shfl_xor(dot_part, 1);
    const int row = rowbase + drow;
    if ((dl & 1) == 0 && row < N_NODES) {
      if (tid < 128) a_src[row] = tot;
      else a_dst[row] = tot;
    }
  }

#pragma unroll
  for (int i = 0; i < 8; ++i) {
    const int row = rowbase + ty * 8 + i;
    if (row < N_NODES) {
      uint2 p;
      p.x = bf16pack(acc[i][0], acc[i][1]);
      p.y = bf16pack(acc[i][2], acc[i][3]);
      ((uint2*)(xpb + (size_t)row * 64))[tx] = p;
    }
  }
}

// ---------------- KR: range assign (block scan + one global atomic) ----------------
__global__ __launch_bounds__(256) void kr_range(const int* __restrict__ counts,
                                                int* __restrict__ row_start,
                                                int* __restrict__ gctr) {
  __shared__ int woff[4];
  __shared__ int s_base;
  const int i = blockIdx.x * 256 + threadIdx.x;
  const int lane = threadIdx.x & 63, w = threadIdx.x >> 6;
  const int c = (i < N_NODES) ? counts[i] : 0;
  int inc = c;
#pragma unroll
  for (int off = 1; off < 64; off <<= 1) {
    int t = __shfl_up(inc, off);
    if (lane >= off) inc += t;
  }
  if (lane == 63) woff[w] = inc;
  __syncthreads();
  if (threadIdx.x == 0) {
    int s = 0;
#pragma unroll
    for (int k = 0; k < 4; ++k) { int t = woff[k]; woff[k] = s; s += t; }
    s_base = atomicAdd(gctr, s);
  }
  __syncthreads();
  if (i < N_NODES) row_start[i] = s_base + woff[w] + inc - c;
}

// ---------------- KD: compute ev, permutation scatter of (src, ev), atomic-free ----
__global__ __launch_bounds__(256) void kd_scatter(
    const int* __restrict__ ei,
    const float* __restrict__ a_src, const float* __restrict__ a_dst,
    const int* __restrict__ row_start, const int* __restrict__ rank,
    int2* __restrict__ sorted) {
  int e = blockIdx.x * 256 + threadIdx.x;
  int s = ei[e];
  int d = ei[E_EDGES + e];
  float a = a_src[s] + a_dst[d];
  a = a > 0.f ? a : NEG_SLOPE * a;
  const float ev = __expf(a);
  sorted[row_start[d] + rank[e]] = make_int2(s, __float_as_int(ev));
}

// ---------------- KE: per-dst gather-reduce, 16 lanes/dst, uint4 gather ----------
__global__ __launch_bounds__(256) void ke_reduce(
    const int* __restrict__ row_start, const int* __restrict__ counts,
    const int2* __restrict__ sorted,
    const unsigned* __restrict__ xpb,   // [N,64] bf16x2
    const float* __restrict__ bias,     // [128]
    float* __restrict__ out) {
  const int tid = threadIdx.x;
  const int w = tid >> 6;
  const int lane = tid & 63;
  const int g = lane >> 4;
  const int gl = lane & 15;
  const int dst = blockIdx.x * 16 + w * 4 + g;
  const int start = row_start[dst];
  const int cnt = counts[dst];

  float acc[8];
#pragma unroll
  for (int i = 0; i < 8; ++i) acc[i] = 0.f;
  float den = 0.f;

  const int2* sp = sorted + start;
  const uint4* xp4 = (const uint4*)xpb;

  if (cnt > 0) {
    int2 se = sp[0];
    for (int j = 0; j + 1 < cnt; ++j) {
      const int2 sn = sp[j + 1];
      const uint4 u = xp4[(size_t)se.x * 16 + gl];
      const float ev = __int_as_float(se.y);
      den += ev;
      acc[0] = fmaf(ev, __uint_as_float(u.x << 16), acc[0]);
      acc[1] = fmaf(ev, __uint_as_float(u.x & 0xffff0000u), acc[1]);
      acc[2] = fmaf(ev, __uint_as_float(u.y << 16), acc[2]);
      acc[3] = fmaf(ev, __uint_as_float(u.y & 0xffff0000u), acc[3]);
      acc[4] = fmaf(ev, __uint_as_float(u.z << 16), acc[4]);
      acc[5] = fmaf(ev, __uint_as_float(u.z & 0xffff0000u), acc[5]);
      acc[6] = fmaf(ev, __uint_as_float(u.w << 16), acc[6]);
      acc[7] = fmaf(ev, __uint_as_float(u.w & 0xffff0000u), acc[7]);
      se = sn;
    }
    {
      const uint4 u = xp4[(size_t)se.x * 16 + gl];
      const float ev = __int_as_float(se.y);
      den += ev;
      acc[0] = fmaf(ev, __uint_as_float(u.x << 16), acc[0]);
      acc[1] = fmaf(ev, __uint_as_float(u.x & 0xffff0000u), acc[1]);
      acc[2] = fmaf(ev, __uint_as_float(u.y << 16), acc[2]);
      acc[3] = fmaf(ev, __uint_as_float(u.y & 0xffff0000u), acc[3]);
      acc[4] = fmaf(ev, __uint_as_float(u.z << 16), acc[4]);
      acc[5] = fmaf(ev, __uint_as_float(u.z & 0xffff0000u), acc[5]);
      acc[6] = fmaf(ev, __uint_as_float(u.w << 16), acc[6]);
      acc[7] = fmaf(ev, __uint_as_float(u.w & 0xffff0000u), acc[7]);
    }
  }

  const float inv = 1.f / (den + SM_EPS);
  const uint4 ur = xp4[(size_t)dst * 16 + gl];
  const float4* br = (const float4*)bias;
  const float4 b0 = br[2 * gl], b1 = br[2 * gl + 1];
  float4 o0, o1;
  o0.x = __uint_as_float(ur.x << 16)          + b0.x + acc[0] * inv;
  o0.y = __uint_as_float(ur.x & 0xffff0000u)  + b0.y + acc[1] * inv;
  o0.z = __uint_as_float(ur.y << 16)          + b0.z + acc[2] * inv;
  o0.w = __uint_as_float(ur.y & 0xffff0000u)  + b0.w + acc[3] * inv;
  o1.x = __uint_as_float(ur.z << 16)          + b1.x + acc[4] * inv;
  o1.y = __uint_as_float(ur.z & 0xffff0000u)  + b1.y + acc[5] * inv;
  o1.z = __uint_as_float(ur.w << 16)          + b1.z + acc[6] * inv;
  o1.w = __uint_as_float(ur.w & 0xffff0000u)  + b1.w + acc[7] * inv;
  float4* orow = (float4*)(out + (size_t)dst * HC);
  orow[2 * gl] = o0;
  orow[2 * gl + 1] = o1;
}

extern "C" void kernel_launch(void* const* d_in, const int* in_sizes, int n_in,
                              void* d_out, int out_size, void* d_ws, size_t ws_size,
                              hipStream_t stream) {
  const float* x         = (const float*)d_in[0];
  const int*   ei        = (const int*)d_in[1];
  const float* v_mapping = (const float*)d_in[2];
  const float* W_src     = (const float*)d_in[3];
  const float* att_src   = (const float*)d_in[4];
  const float* att_dst   = (const float*)d_in[5];
  const float* bias      = (const float*)d_in[6];
  float* out = (float*)d_out;

  char* ws = (char*)d_ws;
  unsigned* xpb        = (unsigned*)ws;  ws += (size_t)N_NODES * 64 * 4;  // 12.8 MB
  float*    a_src      = (float*)ws;     ws += (size_t)N_NODES * 4;
  float*    a_dst      = (float*)ws;     ws += (size_t)N_NODES * 4;
  float*    wvec_src   = (float*)ws;     ws += 256 * 4;
  float*    wvec_dst   = (float*)ws;     ws += 256 * 4;
  int*      counts     = (int*)ws;       ws += (size_t)N_NODES * 4;
  int*      row_start  = (int*)ws;       ws += (size_t)N_NODES * 4;
  int*      gctr       = (int*)ws;       ws += 256;
  int*      rank       = (int*)ws;       ws += (size_t)E_EDGES * 4;       // 6.4 MB
  int2*     sorted     = (int2*)ws;      ws += (size_t)E_EDGES * 8;       // 12.8 MB

  k0_init<<<(N_NODES + 255) / 256, 256, 0, stream>>>(v_mapping, att_src, att_dst,
                                                     wvec_src, wvec_dst, counts, gctr);
  k1_fused<<<NB_GEMM + NB_HIST, 256, 0, stream>>>(x, W_src, wvec_src, wvec_dst,
                                                  xpb, a_src, a_dst, ei, counts, rank);
  kr_range<<<(N_NODES + 255) / 256, 256, 0, stream>>>(counts, row_start, gctr);
  kd_scatter<<<E_EDGES / 256, 256, 0, stream>>>(ei, a_src, a_dst, row_start, rank, sorted);
  ke_reduce<<<N_NODES / 16, 256, 0, stream>>>(row_start, counts, sorted,
                                              xpb, bias, out);
}

// Round 10
// 172.403 us; speedup vs baseline: 1.7099x; 1.2610x over previous
//
#include <hip/hip_runtime.h>

#define N_NODES 50000
#define E_EDGES 1600000
#define HC 128
#define NEG_SLOPE 0.2f
#define SM_EPS 1e-16f
#define NBKT 391          // ceil(50000/128) coarse buckets (dst>>7)
#define BKT_STRIDE 4800   // slack per bucket (avg 4096, +11 sigma)
#define EPB1 4096         // edges per kc1 block
#define NB1 391           // ceil(1600000/4096)

__device__ inline unsigned bf16pack(float a, float b) {
  unsigned ua = __float_as_uint(a), ub = __float_as_uint(b);
  ua = (ua + 0x7fffu + ((ua >> 16) & 1u)) >> 16;
  ub = (ub + 0x7fffu + ((ub >> 16) & 1u)) >> 16;
  return ua | (ub << 16);
}

// ---------------- K0: init gcursor (fixed bucket bases); block 0 computes wvec ----
__global__ __launch_bounds__(256) void k0_init(
    const float* __restrict__ v_mapping,  // [64,256]
    const float* __restrict__ att_src,    // [64]
    const float* __restrict__ att_dst,    // [64]
    float* __restrict__ wvec_src, float* __restrict__ wvec_dst,
    int* __restrict__ gcursor) {
  const int i = blockIdx.x * 256 + threadIdx.x;
  if (i < NBKT) gcursor[i] = i * BKT_STRIDE;
  if (blockIdx.x != 0) return;
  const int j = threadIdx.x;
  float ns = 0.f, nd = 0.f;
  for (int f = 0; f < 64; ++f) {
    float a = att_src[f]; ns = fmaf(a, a, ns);
    float b = att_dst[f]; nd = fmaf(b, b, nd);
  }
  ns = fmaxf(sqrtf(ns), 1e-12f);
  nd = fmaxf(sqrtf(nd), 1e-12f);
  float ws_ = 0.f, wd_ = 0.f;
  for (int f = 0; f < 64; ++f) {
    float v = v_mapping[f * 256 + j];
    ws_ = fmaf(v, att_src[f], ws_);
    wd_ = fmaf(v, att_dst[f], wd_);
  }
  wvec_src[j] = ws_ / ns;
  wvec_dst[j] = wd_ / nd;
}

// ---------------- K1: node phase (register-tiled GEMM + dots), R6 structure -------
__global__ __launch_bounds__(256) void k1_node(
    const float* __restrict__ x,      // [N,256]
    const float* __restrict__ W,      // [256,128]
    const float* __restrict__ wvec_src, const float* __restrict__ wvec_dst,
    unsigned* __restrict__ xpb,       // [N,64]  bf16x2 packed
    float* __restrict__ a_src, float* __restrict__ a_dst) {
  __shared__ float xs[64][68];
  const int tid = threadIdx.x;
  const int rowbase = blockIdx.x * 64;
  const int ty = tid >> 5, tx = tid & 31;

  float acc[8][4];
#pragma unroll
  for (int i = 0; i < 8; ++i)
#pragma unroll
    for (int j = 0; j < 4; ++j) acc[i][j] = 0.f;

  float dot_part = 0.f;
  const int dl = tid & 127;
  const int drow = dl >> 1;
  const int dkh = (dl & 1) * 32;
  const float* wv = (tid < 128) ? wvec_src : wvec_dst;

  const float4* W4 = (const float4*)W;
  const float4* x4 = (const float4*)x;

  for (int chunk = 0; chunk < 4; ++chunk) {
    const int cb16 = chunk * 16;
#pragma unroll
    for (int p = 0; p < 4; ++p) {
      const int row = (tid >> 4) + p * 16;
      const int k4 = tid & 15;
      float4 v = make_float4(0.f, 0.f, 0.f, 0.f);
      if (rowbase + row < N_NODES) v = x4[(size_t)(rowbase + row) * 64 + cb16 + k4];
      *(float4*)&xs[row][k4 * 4] = v;
    }
    __syncthreads();

#pragma unroll 4
    for (int k = 0; k < 64; ++k) {
      const float4 w4 = W4[(size_t)(chunk * 64 + k) * 32 + tx];
      float xv[8];
#pragma unroll
      for (int i = 0; i < 8; ++i) xv[i] = xs[ty * 8 + i][k];
#pragma unroll
      for (int i = 0; i < 8; ++i) {
        acc[i][0] = fmaf(xv[i], w4.x, acc[i][0]);
        acc[i][1] = fmaf(xv[i], w4.y, acc[i][1]);
        acc[i][2] = fmaf(xv[i], w4.z, acc[i][2]);
        acc[i][3] = fmaf(xv[i], w4.w, acc[i][3]);
      }
    }

#pragma unroll 8
    for (int j = 0; j < 32; ++j)
      dot_part = fmaf(xs[drow][dkh + j], wv[chunk * 64 + dkh + j], dot_part);
    __syncthreads();
  }

  {
    float tot = dot_part + __shfl_xor(dot_part, 1);
    const int row = rowbase + drow;
    if ((dl & 1) == 0 && row < N_NODES) {
      if (tid < 128) a_src[row] = tot;
      else a_dst[row] = tot;
    }
  }

#pragma unroll
  for (int i = 0; i < 8; ++i) {
    const int row = rowbase + ty * 8 + i;
    if (row < N_NODES) {
      uint2 p;
      p.x = bf16pack(acc[i][0], acc[i][1]);
      p.y = bf16pack(acc[i][2], acc[i][3]);
      ((uint2*)(xpb + (size_t)row * 64))[tx] = p;
    }
  }
}

// ---------------- KC1: coarse bucket scatter (LDS hist + 1 global claim/bucket) ----
__global__ __launch_bounds__(256) void kc1_coarse(
    const int* __restrict__ ei,
    const float* __restrict__ a_src, const float* __restrict__ a_dst,
    int* __restrict__ gcursor, int2* __restrict__ coarse) {
  __shared__ int chist[NBKT];
  __shared__ int gbase[NBKT];
  __shared__ int ccur[NBKT];
  const int tid = threadIdx.x;
  const int ebase = blockIdx.x * EPB1;
  for (int b = tid; b < NBKT; b += 256) { chist[b] = 0; ccur[b] = 0; }
  __syncthreads();

  // pass A: LDS histogram of this block's edges (coalesced dst loads)
#pragma unroll
  for (int i = 0; i < 16; ++i) {
    const int e = ebase + i * 256 + tid;
    if (e < E_EDGES) atomicAdd(&chist[ei[E_EDGES + e] >> 7], 1);
  }
  __syncthreads();

  // claim one global range per nonempty bucket (~391 returned atomics per block)
  for (int b = tid; b < NBKT; b += 256) {
    const int c = chist[b];
    if (c > 0) gbase[b] = atomicAdd(&gcursor[b], c);
  }
  __syncthreads();

  // pass B: compute ev, scatter (src|dloc, ev) into claimed windows
#pragma unroll
  for (int i = 0; i < 16; ++i) {
    const int e = ebase + i * 256 + tid;
    if (e < E_EDGES) {
      const int s = ei[e];
      const int d = ei[E_EDGES + e];
      const int b = d >> 7;
      float a = a_src[s] + a_dst[d];
      a = a > 0.f ? a : NEG_SLOPE * a;
      const float ev = __expf(a);
      const int pos = gbase[b] + atomicAdd(&ccur[b], 1);
      if (pos < (b + 1) * BKT_STRIDE)  // slack guard
        coarse[pos] = make_int2(s | ((d & 127) << 16), __float_as_int(ev));
    }
  }
}

// ---------------- KC2: per-bucket LDS counting-sort + gather-reduce --------------
__global__ __launch_bounds__(256) void kc2_reduce(
    const int* __restrict__ gcursor, const int2* __restrict__ coarse,
    const unsigned* __restrict__ xpb,   // [N,64] bf16x2
    const float* __restrict__ bias,     // [128]
    float* __restrict__ out) {
  __shared__ unsigned sorted[BKT_STRIDE];  // {src:16 | ev_bf16:16}
  __shared__ int hist[128], cur[128];
  __shared__ int base[129];
  const int b = blockIdx.x;
  const int tid = threadIdx.x;
  const int cstart = b * BKT_STRIDE;
  const int cnt = min(gcursor[b] - cstart, BKT_STRIDE);

  if (tid < 128) { hist[tid] = 0; cur[tid] = 0; }
  __syncthreads();

  // pass A: local dst histogram
  for (int j = tid; j < cnt; j += 256)
    atomicAdd(&hist[(coarse[cstart + j].x >> 16) & 127], 1);
  __syncthreads();

  // exclusive scan of 128 counters by wave 0 (2 elems/lane)
  if (tid < 64) {
    const int h0 = hist[2 * tid], h1 = hist[2 * tid + 1];
    const int pair = h0 + h1;
    int inc = pair;
#pragma unroll
    for (int off = 1; off < 64; off <<= 1) {
      int t = __shfl_up(inc, off);
      if (tid >= off) inc += t;
    }
    const int excl = inc - pair;
    base[2 * tid] = excl;
    base[2 * tid + 1] = excl + h0;
    if (tid == 63) base[128] = inc;
  }
  __syncthreads();

  // pass B: scatter into LDS sorted order, ev -> bf16
  for (int j = tid; j < cnt; j += 256) {
    const int2 e2 = coarse[cstart + j];
    const int dloc = (e2.x >> 16) & 127;
    unsigned uev = (unsigned)e2.y;
    uev = (uev + 0x7fffu + ((uev >> 16) & 1u)) >> 16;
    const int p = base[dloc] + atomicAdd(&cur[dloc], 1);
    sorted[p] = (unsigned)(e2.x & 0xffff) | (uev << 16);
  }
  __syncthreads();

  // reduce: 16-lane group per dst, lane owns 8 channels (uint4 = 16B gather)
  const int g = tid >> 4, gl = tid & 15;
  const uint4* xp4 = (const uint4*)xpb;
  const float4* br = (const float4*)bias;
  const float4 b0 = br[2 * gl], b1 = br[2 * gl + 1];

  for (int dl = g; dl < 128; dl += 16) {
    const int dst = (b << 7) | dl;
    if (dst >= N_NODES) break;
    const int s0 = base[dl];
    const int cntd = base[dl + 1] - s0;

    float acc[8];
#pragma unroll
    for (int i = 0; i < 8; ++i) acc[i] = 0.f;
    float den = 0.f;

    for (int j = 0; j < cntd; ++j) {
      const unsigned u = sorted[s0 + j];          // broadcast across the 16 lanes
      const float ev = __uint_as_float(u & 0xffff0000u);
      const uint4 v = xp4[(size_t)(u & 0xffffu) * 16 + gl];
      den += ev;
      acc[0] = fmaf(ev, __uint_as_float(v.x << 16), acc[0]);
      acc[1] = fmaf(ev, __uint_as_float(v.x & 0xffff0000u), acc[1]);
      acc[2] = fmaf(ev, __uint_as_float(v.y << 16), acc[2]);
      acc[3] = fmaf(ev, __uint_as_float(v.y & 0xffff0000u), acc[3]);
      acc[4] = fmaf(ev, __uint_as_float(v.z << 16), acc[4]);
      acc[5] = fmaf(ev, __uint_as_float(v.z & 0xffff0000u), acc[5]);
      acc[6] = fmaf(ev, __uint_as_float(v.w << 16), acc[6]);
      acc[7] = fmaf(ev, __uint_as_float(v.w & 0xffff0000u), acc[7]);
    }

    const float inv = 1.f / (den + SM_EPS);
    const uint4 ur = xp4[(size_t)dst * 16 + gl];
    float4 o0, o1;
    o0.x = __uint_as_float(ur.x << 16)         + b0.x + acc[0] * inv;
    o0.y = __uint_as_float(ur.x & 0xffff0000u) + b0.y + acc[1] * inv;
    o0.z = __uint_as_float(ur.y << 16)         + b0.z + acc[2] * inv;
    o0.w = __uint_as_float(ur.y & 0xffff0000u) + b0.w + acc[3] * inv;
    o1.x = __uint_as_float(ur.z << 16)         + b1.x + acc[4] * inv;
    o1.y = __uint_as_float(ur.z & 0xffff0000u) + b1.y + acc[5] * inv;
    o1.z = __uint_as_float(ur.w << 16)         + b1.z + acc[6] * inv;
    o1.w = __uint_as_float(ur.w & 0xffff0000u) + b1.w + acc[7] * inv;
    float4* orow = (float4*)(out + (size_t)dst * HC);
    orow[2 * gl] = o0;
    orow[2 * gl + 1] = o1;
  }
}

extern "C" void kernel_launch(void* const* d_in, const int* in_sizes, int n_in,
                              void* d_out, int out_size, void* d_ws, size_t ws_size,
                              hipStream_t stream) {
  const float* x         = (const float*)d_in[0];
  const int*   ei        = (const int*)d_in[1];
  const float* v_mapping = (const float*)d_in[2];
  const float* W_src     = (const float*)d_in[3];
  const float* att_src   = (const float*)d_in[4];
  const float* att_dst   = (const float*)d_in[5];
  const float* bias      = (const float*)d_in[6];
  float* out = (float*)d_out;

  char* ws = (char*)d_ws;
  unsigned* xpb      = (unsigned*)ws;  ws += (size_t)N_NODES * 64 * 4;      // 12.8 MB
  float*    a_src    = (float*)ws;     ws += (size_t)N_NODES * 4;
  float*    a_dst    = (float*)ws;     ws += (size_t)N_NODES * 4;
  float*    wvec_src = (float*)ws;     ws += 256 * 4;
  float*    wvec_dst = (float*)ws;     ws += 256 * 4;
  int*      gcursor  = (int*)ws;       ws += ((NBKT + 127) / 128) * 128 * 4;
  int2*     coarse   = (int2*)ws;      ws += (size_t)NBKT * BKT_STRIDE * 8; // 15.0 MB

  k0_init<<<2, 256, 0, stream>>>(v_mapping, att_src, att_dst,
                                 wvec_src, wvec_dst, gcursor);
  k1_node<<<(N_NODES + 63) / 64, 256, 0, stream>>>(x, W_src, wvec_src, wvec_dst,
                                                   xpb, a_src, a_dst);
  kc1_coarse<<<NB1, 256, 0, stream>>>(ei, a_src, a_dst, gcursor, coarse);
  kc2_reduce<<<NBKT, 256, 0, stream>>>(gcursor, coarse, xpb, bias, out);
}

// Round 11
// 157.811 us; speedup vs baseline: 1.8680x; 1.0925x over previous
//
#include <hip/hip_runtime.h>

#define N_NODES 50000
#define E_EDGES 1600000
#define HC 128
#define NEG_SLOPE 0.2f
#define SM_EPS 1e-16f
#define NBKT 391          // ceil(50000/128) coarse buckets (dst>>7)
#define BKT_STRIDE 4800   // slack per bucket (avg 4096, +11 sigma)
#define EPB1 4096         // edges per kc1 block
#define NB1 391           // ceil(1600000/4096)

typedef __attribute__((ext_vector_type(8))) short short8v;
typedef __attribute__((ext_vector_type(4))) float f32x4;

__device__ inline unsigned bf16pack(float a, float b) {
  unsigned ua = __float_as_uint(a), ub = __float_as_uint(b);
  ua = (ua + 0x7fffu + ((ua >> 16) & 1u)) >> 16;
  ub = (ub + 0x7fffu + ((ub >> 16) & 1u)) >> 16;
  return ua | (ub << 16);
}

// ---------------- K0: build wT[144][256] bf16 (W^T with wvec cols); init gcursor --
__global__ __launch_bounds__(256) void k0_init(
    const float* __restrict__ v_mapping,  // [64,256]
    const float* __restrict__ att_src,    // [64]
    const float* __restrict__ att_dst,    // [64]
    const float* __restrict__ W,          // [256,128]
    unsigned short* __restrict__ wT,      // [144,256] bf16
    int* __restrict__ gcursor) {
  const int tid = threadIdx.x, bid = blockIdx.x;
  if (bid == 0)
    for (int i = tid; i < NBKT; i += 256) gcursor[i] = i * BKT_STRIDE;

  __shared__ float wv[2][256];
  {
    const int j = tid;
    float ns = 0.f, nd = 0.f;
    for (int f = 0; f < 64; ++f) {
      float a = att_src[f]; ns = fmaf(a, a, ns);
      float b = att_dst[f]; nd = fmaf(b, b, nd);
    }
    ns = fmaxf(sqrtf(ns), 1e-12f);
    nd = fmaxf(sqrtf(nd), 1e-12f);
    float s = 0.f, d = 0.f;
    for (int f = 0; f < 64; ++f) {
      float v = v_mapping[f * 256 + j];
      s = fmaf(v, att_src[f], s);
      d = fmaf(v, att_dst[f], d);
    }
    wv[0][j] = s / ns;
    wv[1][j] = d / nd;
  }
  __syncthreads();

  // rows n = bid*8 .. +7 of wT; thread handles k = tid
#pragma unroll
  for (int r = 0; r < 8; ++r) {
    const int n = bid * 8 + r;
    const int k = tid;
    float v;
    if (n < 128) v = W[k * 128 + n];
    else if (n == 128) v = wv[0][k];
    else if (n == 129) v = wv[1][k];
    else v = 0.f;
    unsigned u = __float_as_uint(v);
    u = (u + 0x7fffu + ((u >> 16) & 1u)) >> 16;
    wT[n * 256 + k] = (unsigned short)u;
  }
}

// ---------------- K1: node GEMM via MFMA (bf16), dots folded as cols 128/129 ------
// block: 64 rows; wave w owns rows w*16..+15, all 144 cols. 72 mfma/wave.
__global__ __launch_bounds__(256) void k1_node(
    const float* __restrict__ x,            // [N,256]
    const unsigned short* __restrict__ wT,  // [144,256] bf16
    unsigned* __restrict__ xpb,             // [N,64] bf16x2 packed
    float* __restrict__ a_src, float* __restrict__ a_dst) {
  __shared__ unsigned short xs[64 * 264];   // bf16, row stride 264 (528B)
  const int tid = threadIdx.x;
  const int w = tid >> 6, lane = tid & 63;
  const int rowbase = blockIdx.x * 64;

  // stage: f32 -> bf16 into LDS
  const float4* x4 = (const float4*)x;
#pragma unroll
  for (int c = 0; c < 16; ++c) {
    const int idx = c * 256 + tid;        // float4 index within 64x256 tile
    const int row = idx >> 6, c4 = idx & 63;
    float4 v = make_float4(0.f, 0.f, 0.f, 0.f);
    if (rowbase + row < N_NODES) v = x4[(size_t)(rowbase + row) * 64 + c4];
    uint2 p;
    p.x = bf16pack(v.x, v.y);
    p.y = bf16pack(v.z, v.w);
    *(uint2*)&xs[row * 264 + c4 * 4] = p;
  }
  __syncthreads();

  f32x4 acc[9];
#pragma unroll
  for (int t = 0; t < 9; ++t) acc[t] = (f32x4){0.f, 0.f, 0.f, 0.f};

  // A: m = lane&15, k = (lane>>4)*8 + e (contiguous). B: n = lane&15, same k.
  const int m = lane & 15, kq = lane >> 4;
  const unsigned short* arow = &xs[(w * 16 + m) * 264 + kq * 8];
#pragma unroll
  for (int ks = 0; ks < 8; ++ks) {
    const short8v af = *(const short8v*)(arow + ks * 32);
#pragma unroll
    for (int ct = 0; ct < 9; ++ct) {
      const short8v bf = *(const short8v*)(wT + (ct * 16 + m) * 256 + ks * 32 + kq * 8);
      acc[ct] = __builtin_amdgcn_mfma_f32_16x16x32_bf16(af, bf, acc[ct], 0, 0, 0);
    }
  }

  // a_src/a_dst live in col-tile 8 at cols 0/1 (global 128/129)
  if (m < 2) {
    float* ap = m ? a_dst : a_src;
#pragma unroll
    for (int i = 0; i < 4; ++i) {
      const int rg = rowbase + w * 16 + kq * 4 + i;
      if (rg < N_NODES) ap[rg] = acc[8][i];
    }
  }

  // C tiles 0..7 -> per-wave LDS f32 [16][132] (aliases this wave's xs rows), then pack
  float* cs = (float*)&xs[w * 16 * 264];
#pragma unroll
  for (int ct = 0; ct < 8; ++ct)
#pragma unroll
    for (int i = 0; i < 4; ++i)
      cs[(kq * 4 + i) * 132 + ct * 16 + m] = acc[ct][i];
  __syncthreads();

  const int prow = lane & 15, q = lane >> 4;
  const int grow = rowbase + w * 16 + prow;
  unsigned uu[16];
#pragma unroll
  for (int u = 0; u < 16; ++u) {
    const float2 f2 = *(const float2*)&cs[prow * 132 + q * 32 + u * 2];
    uu[u] = bf16pack(f2.x, f2.y);
  }
  if (grow < N_NODES) {
    uint4* d4 = (uint4*)&xpb[(size_t)grow * 64 + q * 16];
    d4[0] = make_uint4(uu[0], uu[1], uu[2], uu[3]);
    d4[1] = make_uint4(uu[4], uu[5], uu[6], uu[7]);
    d4[2] = make_uint4(uu[8], uu[9], uu[10], uu[11]);
    d4[3] = make_uint4(uu[12], uu[13], uu[14], uu[15]);
  }
}

// ---------------- KC1: coarse bucket scatter (LDS hist + 1 global claim/bucket) ----
__global__ __launch_bounds__(256) void kc1_coarse(
    const int* __restrict__ ei,
    const float* __restrict__ a_src, const float* __restrict__ a_dst,
    int* __restrict__ gcursor, int2* __restrict__ coarse) {
  __shared__ int chist[NBKT];
  __shared__ int gbase[NBKT];
  __shared__ int ccur[NBKT];
  const int tid = threadIdx.x;
  const int ebase = blockIdx.x * EPB1;
  for (int b = tid; b < NBKT; b += 256) { chist[b] = 0; ccur[b] = 0; }
  __syncthreads();

#pragma unroll
  for (int i = 0; i < 16; ++i) {
    const int e = ebase + i * 256 + tid;
    if (e < E_EDGES) atomicAdd(&chist[ei[E_EDGES + e] >> 7], 1);
  }
  __syncthreads();

  for (int b = tid; b < NBKT; b += 256) {
    const int c = chist[b];
    if (c > 0) gbase[b] = atomicAdd(&gcursor[b], c);
  }
  __syncthreads();

#pragma unroll
  for (int i = 0; i < 16; ++i) {
    const int e = ebase + i * 256 + tid;
    if (e < E_EDGES) {
      const int s = ei[e];
      const int d = ei[E_EDGES + e];
      const int b = d >> 7;
      float a = a_src[s] + a_dst[d];
      a = a > 0.f ? a : NEG_SLOPE * a;
      const float ev = __expf(a);
      const int pos = gbase[b] + atomicAdd(&ccur[b], 1);
      if (pos < (b + 1) * BKT_STRIDE)
        coarse[pos] = make_int2(s | ((d & 127) << 16), __float_as_int(ev));
    }
  }
}

// ---------------- KC2: per-bucket LDS counting-sort + gather-reduce --------------
__global__ __launch_bounds__(256) void kc2_reduce(
    const int* __restrict__ gcursor, const int2* __restrict__ coarse,
    const unsigned* __restrict__ xpb,   // [N,64] bf16x2
    const float* __restrict__ bias,     // [128]
    float* __restrict__ out) {
  __shared__ unsigned sorted[BKT_STRIDE];  // {src:16 | ev_bf16:16}
  __shared__ int hist[128], cur[128];
  __shared__ int base[129];
  const int b = blockIdx.x;
  const int tid = threadIdx.x;
  const int cstart = b * BKT_STRIDE;
  const int cnt = min(gcursor[b] - cstart, BKT_STRIDE);

  if (tid < 128) { hist[tid] = 0; cur[tid] = 0; }
  __syncthreads();

  for (int j = tid; j < cnt; j += 256)
    atomicAdd(&hist[(coarse[cstart + j].x >> 16) & 127], 1);
  __syncthreads();

  if (tid < 64) {
    const int h0 = hist[2 * tid], h1 = hist[2 * tid + 1];
    const int pair = h0 + h1;
    int inc = pair;
#pragma unroll
    for (int off = 1; off < 64; off <<= 1) {
      int t = __shfl_up(inc, off);
      if (tid >= off) inc += t;
    }
    const int excl = inc - pair;
    base[2 * tid] = excl;
    base[2 * tid + 1] = excl + h0;
    if (tid == 63) base[128] = inc;
  }
  __syncthreads();

  for (int j = tid; j < cnt; j += 256) {
    const int2 e2 = coarse[cstart + j];
    const int dloc = (e2.x >> 16) & 127;
    unsigned uev = (unsigned)e2.y;
    uev = (uev + 0x7fffu + ((uev >> 16) & 1u)) >> 16;
    const int p = base[dloc] + atomicAdd(&cur[dloc], 1);
    sorted[p] = (unsigned)(e2.x & 0xffff) | (uev << 16);
  }
  __syncthreads();

  const int g = tid >> 4, gl = tid & 15;
  const uint4* xp4 = (const uint4*)xpb;
  const float4* br = (const float4*)bias;
  const float4 b0 = br[2 * gl], b1 = br[2 * gl + 1];

  for (int dl = g; dl < 128; dl += 16) {
    const int dst = (b << 7) | dl;
    if (dst >= N_NODES) break;
    const int s0 = base[dl];
    const int cntd = base[dl + 1] - s0;

    float acc[8];
#pragma unroll
    for (int i = 0; i < 8; ++i) acc[i] = 0.f;
    float den = 0.f;

    for (int j = 0; j < cntd; ++j) {
      const unsigned u = sorted[s0 + j];
      const float ev = __uint_as_float(u & 0xffff0000u);
      const uint4 v = xp4[(size_t)(u & 0xffffu) * 16 + gl];
      den += ev;
      acc[0] = fmaf(ev, __uint_as_float(v.x << 16), acc[0]);
      acc[1] = fmaf(ev, __uint_as_float(v.x & 0xffff0000u), acc[1]);
      acc[2] = fmaf(ev, __uint_as_float(v.y << 16), acc[2]);
      acc[3] = fmaf(ev, __uint_as_float(v.y & 0xffff0000u), acc[3]);
      acc[4] = fmaf(ev, __uint_as_float(v.z << 16), acc[4]);
      acc[5] = fmaf(ev, __uint_as_float(v.z & 0xffff0000u), acc[5]);
      acc[6] = fmaf(ev, __uint_as_float(v.w << 16), acc[6]);
      acc[7] = fmaf(ev, __uint_as_float(v.w & 0xffff0000u), acc[7]);
    }

    const float inv = 1.f / (den + SM_EPS);
    const uint4 ur = xp4[(size_t)dst * 16 + gl];
    float4 o0, o1;
    o0.x = __uint_as_float(ur.x << 16)         + b0.x + acc[0] * inv;
    o0.y = __uint_as_float(ur.x & 0xffff0000u) + b0.y + acc[1] * inv;
    o0.z = __uint_as_float(ur.y << 16)         + b0.z + acc[2] * inv;
    o0.w = __uint_as_float(ur.y & 0xffff0000u) + b0.w + acc[3] * inv;
    o1.x = __uint_as_float(ur.z << 16)         + b1.x + acc[4] * inv;
    o1.y = __uint_as_float(ur.z & 0xffff0000u) + b1.y + acc[5] * inv;
    o1.z = __uint_as_float(ur.w << 16)         + b1.z + acc[6] * inv;
    o1.w = __uint_as_float(ur.w & 0xffff0000u) + b1.w + acc[7] * inv;
    float4* orow = (float4*)(out + (size_t)dst * HC);
    orow[2 * gl] = o0;
    orow[2 * gl + 1] = o1;
  }
}

extern "C" void kernel_launch(void* const* d_in, const int* in_sizes, int n_in,
                              void* d_out, int out_size, void* d_ws, size_t ws_size,
                              hipStream_t stream) {
  const float* x         = (const float*)d_in[0];
  const int*   ei        = (const int*)d_in[1];
  const float* v_mapping = (const float*)d_in[2];
  const float* W_src     = (const float*)d_in[3];
  const float* att_src   = (const float*)d_in[4];
  const float* att_dst   = (const float*)d_in[5];
  const float* bias      = (const float*)d_in[6];
  float* out = (float*)d_out;

  char* ws = (char*)d_ws;
  unsigned*       xpb     = (unsigned*)ws;        ws += (size_t)N_NODES * 64 * 4;  // 12.8 MB
  float*          a_src   = (float*)ws;           ws += (size_t)N_NODES * 4;
  float*          a_dst   = (float*)ws;           ws += (size_t)N_NODES * 4;
  unsigned short* wT      = (unsigned short*)ws;  ws += 144 * 256 * 2;             // 73.7 KB
  int*            gcursor = (int*)ws;             ws += ((NBKT + 127) / 128) * 128 * 4;
  int2*           coarse  = (int2*)ws;            ws += (size_t)NBKT * BKT_STRIDE * 8;

  k0_init<<<18, 256, 0, stream>>>(v_mapping, att_src, att_dst, W_src, wT, gcursor);
  k1_node<<<(N_NODES + 63) / 64, 256, 0, stream>>>(x, wT, xpb, a_src, a_dst);
  kc1_coarse<<<NB1, 256, 0, stream>>>(ei, a_src, a_dst, gcursor, coarse);
  kc2_reduce<<<NBKT, 256, 0, stream>>>(gcursor, coarse, xpb, bias, out);
}

// Round 12
// 152.178 us; speedup vs baseline: 1.9371x; 1.0370x over previous
//
#include <hip/hip_runtime.h>

#define N_NODES 50000
#define E_EDGES 1600000
#define HC 128
#define NEG_SLOPE 0.2f
#define SM_EPS 1e-16f
#define NBKT 782          // ceil(50000/64) coarse buckets (dst>>6)
#define BKT_STRIDE 2600   // slack per bucket (avg 2048, +12 sigma)
#define EPB1 4096         // edges per kc1 block
#define NB1 391           // ceil(1600000/4096)

typedef __attribute__((ext_vector_type(8))) short short8v;
typedef __attribute__((ext_vector_type(4))) float f32x4;

__device__ inline unsigned bf16pack(float a, float b) {
  unsigned ua = __float_as_uint(a), ub = __float_as_uint(b);
  ua = (ua + 0x7fffu + ((ua >> 16) & 1u)) >> 16;
  ub = (ub + 0x7fffu + ((ub >> 16) & 1u)) >> 16;
  return ua | (ub << 16);
}

// ---------------- K0: build wT[144][256] bf16 (W^T with wvec cols); init gcursor --
__global__ __launch_bounds__(256) void k0_init(
    const float* __restrict__ v_mapping,  // [64,256]
    const float* __restrict__ att_src,    // [64]
    const float* __restrict__ att_dst,    // [64]
    const float* __restrict__ W,          // [256,128]
    unsigned short* __restrict__ wT,      // [144,256] bf16
    int* __restrict__ gcursor) {
  const int tid = threadIdx.x, bid = blockIdx.x;
  if (bid == 0)
    for (int i = tid; i < NBKT; i += 256) gcursor[i] = i * BKT_STRIDE;

  __shared__ float wv[2][256];
  {
    const int j = tid;
    float ns = 0.f, nd = 0.f;
    for (int f = 0; f < 64; ++f) {
      float a = att_src[f]; ns = fmaf(a, a, ns);
      float b = att_dst[f]; nd = fmaf(b, b, nd);
    }
    ns = fmaxf(sqrtf(ns), 1e-12f);
    nd = fmaxf(sqrtf(nd), 1e-12f);
    float s = 0.f, d = 0.f;
    for (int f = 0; f < 64; ++f) {
      float v = v_mapping[f * 256 + j];
      s = fmaf(v, att_src[f], s);
      d = fmaf(v, att_dst[f], d);
    }
    wv[0][j] = s / ns;
    wv[1][j] = d / nd;
  }
  __syncthreads();

#pragma unroll
  for (int r = 0; r < 8; ++r) {
    const int n = bid * 8 + r;
    const int k = tid;
    float v;
    if (n < 128) v = W[k * 128 + n];
    else if (n == 128) v = wv[0][k];
    else if (n == 129) v = wv[1][k];
    else v = 0.f;
    unsigned u = __float_as_uint(v);
    u = (u + 0x7fffu + ((u >> 16) & 1u)) >> 16;
    wT[n * 256 + k] = (unsigned short)u;
  }
}

// ---------------- K1: node GEMM via MFMA (bf16), dots folded as cols 128/129 ------
__global__ __launch_bounds__(256) void k1_node(
    const float* __restrict__ x,            // [N,256]
    const unsigned short* __restrict__ wT,  // [144,256] bf16
    unsigned* __restrict__ xpb,             // [N,64] bf16x2 packed
    float* __restrict__ a_src, float* __restrict__ a_dst) {
  __shared__ unsigned short xs[64 * 264];   // bf16, row stride 264 (528B)
  const int tid = threadIdx.x;
  const int w = tid >> 6, lane = tid & 63;
  const int rowbase = blockIdx.x * 64;

  const float4* x4 = (const float4*)x;
#pragma unroll
  for (int c = 0; c < 16; ++c) {
    const int idx = c * 256 + tid;
    const int row = idx >> 6, c4 = idx & 63;
    float4 v = make_float4(0.f, 0.f, 0.f, 0.f);
    if (rowbase + row < N_NODES) v = x4[(size_t)(rowbase + row) * 64 + c4];
    uint2 p;
    p.x = bf16pack(v.x, v.y);
    p.y = bf16pack(v.z, v.w);
    *(uint2*)&xs[row * 264 + c4 * 4] = p;
  }
  __syncthreads();

  f32x4 acc[9];
#pragma unroll
  for (int t = 0; t < 9; ++t) acc[t] = (f32x4){0.f, 0.f, 0.f, 0.f};

  const int m = lane & 15, kq = lane >> 4;
  const unsigned short* arow = &xs[(w * 16 + m) * 264 + kq * 8];
#pragma unroll
  for (int ks = 0; ks < 8; ++ks) {
    const short8v af = *(const short8v*)(arow + ks * 32);
#pragma unroll
    for (int ct = 0; ct < 9; ++ct) {
      const short8v bf = *(const short8v*)(wT + (ct * 16 + m) * 256 + ks * 32 + kq * 8);
      acc[ct] = __builtin_amdgcn_mfma_f32_16x16x32_bf16(af, bf, acc[ct], 0, 0, 0);
    }
  }

  if (m < 2) {
    float* ap = m ? a_dst : a_src;
#pragma unroll
    for (int i = 0; i < 4; ++i) {
      const int rg = rowbase + w * 16 + kq * 4 + i;
      if (rg < N_NODES) ap[rg] = acc[8][i];
    }
  }

  float* cs = (float*)&xs[w * 16 * 264];
#pragma unroll
  for (int ct = 0; ct < 8; ++ct)
#pragma unroll
    for (int i = 0; i < 4; ++i)
      cs[(kq * 4 + i) * 132 + ct * 16 + m] = acc[ct][i];
  __syncthreads();

  const int prow = lane & 15, q = lane >> 4;
  const int grow = rowbase + w * 16 + prow;
  unsigned uu[16];
#pragma unroll
  for (int u = 0; u < 16; ++u) {
    const float2 f2 = *(const float2*)&cs[prow * 132 + q * 32 + u * 2];
    uu[u] = bf16pack(f2.x, f2.y);
  }
  if (grow < N_NODES) {
    uint4* d4 = (uint4*)&xpb[(size_t)grow * 64 + q * 16];
    d4[0] = make_uint4(uu[0], uu[1], uu[2], uu[3]);
    d4[1] = make_uint4(uu[4], uu[5], uu[6], uu[7]);
    d4[2] = make_uint4(uu[8], uu[9], uu[10], uu[11]);
    d4[3] = make_uint4(uu[12], uu[13], uu[14], uu[15]);
  }
}

// ---------------- KC1: coarse bucket scatter (LDS hist + 1 global claim/bucket) ----
__global__ __launch_bounds__(256) void kc1_coarse(
    const int* __restrict__ ei,
    const float* __restrict__ a_src, const float* __restrict__ a_dst,
    int* __restrict__ gcursor, int2* __restrict__ coarse) {
  __shared__ int chist[NBKT];
  __shared__ int gbase[NBKT];
  __shared__ int ccur[NBKT];
  const int tid = threadIdx.x;
  const int ebase = blockIdx.x * EPB1;
  for (int b = tid; b < NBKT; b += 256) { chist[b] = 0; ccur[b] = 0; }
  __syncthreads();

#pragma unroll
  for (int i = 0; i < 16; ++i) {
    const int e = ebase + i * 256 + tid;
    if (e < E_EDGES) atomicAdd(&chist[ei[E_EDGES + e] >> 6], 1);
  }
  __syncthreads();

  for (int b = tid; b < NBKT; b += 256) {
    const int c = chist[b];
    if (c > 0) gbase[b] = atomicAdd(&gcursor[b], c);
  }
  __syncthreads();

#pragma unroll
  for (int i = 0; i < 16; ++i) {
    const int e = ebase + i * 256 + tid;
    if (e < E_EDGES) {
      const int s = ei[e];
      const int d = ei[E_EDGES + e];
      const int b = d >> 6;
      float a = a_src[s] + a_dst[d];
      a = a > 0.f ? a : NEG_SLOPE * a;
      const float ev = __expf(a);
      const int pos = gbase[b] + atomicAdd(&ccur[b], 1);
      if (pos < (b + 1) * BKT_STRIDE)
        coarse[pos] = make_int2(s | ((d & 63) << 16), __float_as_int(ev));
    }
  }
}

// ---------------- KC2: per-bucket LDS counting-sort + gather-reduce --------------
__global__ __launch_bounds__(256) void kc2_reduce(
    const int* __restrict__ gcursor, const int2* __restrict__ coarse,
    const unsigned* __restrict__ xpb,   // [N,64] bf16x2
    const float* __restrict__ bias,     // [128]
    float* __restrict__ out) {
  __shared__ unsigned sorted[BKT_STRIDE];  // {src:16 | ev_bf16:16}
  __shared__ int hist[64], cur[64];
  __shared__ int base[65];
  const int b = blockIdx.x;
  const int tid = threadIdx.x;
  const int cstart = b * BKT_STRIDE;
  const int cnt = min(gcursor[b] - cstart, BKT_STRIDE);

  if (tid < 64) { hist[tid] = 0; cur[tid] = 0; }
  __syncthreads();

  for (int j = tid; j < cnt; j += 256)
    atomicAdd(&hist[(coarse[cstart + j].x >> 16) & 63], 1);
  __syncthreads();

  if (tid < 64) {
    const int h = hist[tid];
    int inc = h;
#pragma unroll
    for (int off = 1; off < 64; off <<= 1) {
      int t = __shfl_up(inc, off);
      if (tid >= off) inc += t;
    }
    base[tid] = inc - h;
    if (tid == 63) base[64] = inc;
  }
  __syncthreads();

  for (int j = tid; j < cnt; j += 256) {
    const int2 e2 = coarse[cstart + j];
    const int dloc = (e2.x >> 16) & 63;
    unsigned uev = (unsigned)e2.y;
    uev = (uev + 0x7fffu + ((uev >> 16) & 1u)) >> 16;
    const int p = base[dloc] + atomicAdd(&cur[dloc], 1);
    sorted[p] = (unsigned)(e2.x & 0xffff) | (uev << 16);
  }
  __syncthreads();

  const int g = tid >> 4, gl = tid & 15;
  const uint4* xp4 = (const uint4*)xpb;
  const float4* br = (const float4*)bias;
  const float4 b0 = br[2 * gl], b1 = br[2 * gl + 1];

  for (int dl = g; dl < 64; dl += 16) {
    const int dst = (b << 6) | dl;
    if (dst >= N_NODES) break;
    const int s0 = base[dl];
    const int cntd = base[dl + 1] - s0;

    float acc[8];
#pragma unroll
    for (int i = 0; i < 8; ++i) acc[i] = 0.f;
    float den = 0.f;

    int j = 0;
    for (; j + 2 <= cntd; j += 2) {
      const unsigned uA = sorted[s0 + j];
      const unsigned uB = sorted[s0 + j + 1];
      const float evA = __uint_as_float(uA & 0xffff0000u);
      const float evB = __uint_as_float(uB & 0xffff0000u);
      const uint4 vA = xp4[(size_t)(uA & 0xffffu) * 16 + gl];
      const uint4 vB = xp4[(size_t)(uB & 0xffffu) * 16 + gl];
      den += evA + evB;
      acc[0] = fmaf(evA, __uint_as_float(vA.x << 16), acc[0]);
      acc[1] = fmaf(evA, __uint_as_float(vA.x & 0xffff0000u), acc[1]);
      acc[2] = fmaf(evA, __uint_as_float(vA.y << 16), acc[2]);
      acc[3] = fmaf(evA, __uint_as_float(vA.y & 0xffff0000u), acc[3]);
      acc[4] = fmaf(evA, __uint_as_float(vA.z << 16), acc[4]);
      acc[5] = fmaf(evA, __uint_as_float(vA.z & 0xffff0000u), acc[5]);
      acc[6] = fmaf(evA, __uint_as_float(vA.w << 16), acc[6]);
      acc[7] = fmaf(evA, __uint_as_float(vA.w & 0xffff0000u), acc[7]);
      acc[0] = fmaf(evB, __uint_as_float(vB.x << 16), acc[0]);
      acc[1] = fmaf(evB, __uint_as_float(vB.x & 0xffff0000u), acc[1]);
      acc[2] = fmaf(evB, __uint_as_float(vB.y << 16), acc[2]);
      acc[3] = fmaf(evB, __uint_as_float(vB.y & 0xffff0000u), acc[3]);
      acc[4] = fmaf(evB, __uint_as_float(vB.z << 16), acc[4]);
      acc[5] = fmaf(evB, __uint_as_float(vB.z & 0xffff0000u), acc[5]);
      acc[6] = fmaf(evB, __uint_as_float(vB.w << 16), acc[6]);
      acc[7] = fmaf(evB, __uint_as_float(vB.w & 0xffff0000u), acc[7]);
    }
    if (j < cntd) {
      const unsigned u = sorted[s0 + j];
      const float ev = __uint_as_float(u & 0xffff0000u);
      const uint4 v = xp4[(size_t)(u & 0xffffu) * 16 + gl];
      den += ev;
      acc[0] = fmaf(ev, __uint_as_float(v.x << 16), acc[0]);
      acc[1] = fmaf(ev, __uint_as_float(v.x & 0xffff0000u), acc[1]);
      acc[2] = fmaf(ev, __uint_as_float(v.y << 16), acc[2]);
      acc[3] = fmaf(ev, __uint_as_float(v.y & 0xffff0000u), acc[3]);
      acc[4] = fmaf(ev, __uint_as_float(v.z << 16), acc[4]);
      acc[5] = fmaf(ev, __uint_as_float(v.z & 0xffff0000u), acc[5]);
      acc[6] = fmaf(ev, __uint_as_float(v.w << 16), acc[6]);
      acc[7] = fmaf(ev, __uint_as_float(v.w & 0xffff0000u), acc[7]);
    }

    const float inv = 1.f / (den + SM_EPS);
    const uint4 ur = xp4[(size_t)dst * 16 + gl];
    float4 o0, o1;
    o0.x = __uint_as_float(ur.x << 16)         + b0.x + acc[0] * inv;
    o0.y = __uint_as_float(ur.x & 0xffff0000u) + b0.y + acc[1] * inv;
    o0.z = __uint_as_float(ur.y << 16)         + b0.z + acc[2] * inv;
    o0.w = __uint_as_float(ur.y & 0xffff0000u) + b0.w + acc[3] * inv;
    o1.x = __uint_as_float(ur.z << 16)         + b1.x + acc[4] * inv;
    o1.y = __uint_as_float(ur.z & 0xffff0000u) + b1.y + acc[5] * inv;
    o1.z = __uint_as_float(ur.w << 16)         + b1.z + acc[6] * inv;
    o1.w = __uint_as_float(ur.w & 0xffff0000u) + b1.w + acc[7] * inv;
    float4* orow = (float4*)(out + (size_t)dst * HC);
    orow[2 * gl] = o0;
    orow[2 * gl + 1] = o1;
  }
}

extern "C" void kernel_launch(void* const* d_in, const int* in_sizes, int n_in,
                              void* d_out, int out_size, void* d_ws, size_t ws_size,
                              hipStream_t stream) {
  const float* x         = (const float*)d_in[0];
  const int*   ei        = (const int*)d_in[1];
  const float* v_mapping = (const float*)d_in[2];
  const float* W_src     = (const float*)d_in[3];
  const float* att_src   = (const float*)d_in[4];
  const float* att_dst   = (const float*)d_in[5];
  const float* bias      = (const float*)d_in[6];
  float* out = (float*)d_out;

  char* ws = (char*)d_ws;
  unsigned*       xpb     = (unsigned*)ws;        ws += (size_t)N_NODES * 64 * 4;  // 12.8 MB
  float*          a_src   = (float*)ws;           ws += (size_t)N_NODES * 4;
  float*          a_dst   = (float*)ws;           ws += (size_t)N_NODES * 4;
  unsigned short* wT      = (unsigned short*)ws;  ws += 144 * 256 * 2;             // 73.7 KB
  int*            gcursor = (int*)ws;             ws += ((NBKT + 127) / 128) * 128 * 4;
  int2*           coarse  = (int2*)ws;            ws += (size_t)NBKT * BKT_STRIDE * 8;  // 16.3 MB

  k0_init<<<18, 256, 0, stream>>>(v_mapping, att_src, att_dst, W_src, wT, gcursor);
  k1_node<<<(N_NODES + 63) / 64, 256, 0, stream>>>(x, wT, xpb, a_src, a_dst);
  kc1_coarse<<<NB1, 256, 0, stream>>>(ei, a_src, a_dst, gcursor, coarse);
  kc2_reduce<<<NBKT, 256, 0, stream>>>(gcursor, coarse, xpb, bias, out);
}

// Round 13
// 143.999 us; speedup vs baseline: 2.0471x; 1.0568x over previous
//
#include <hip/hip_runtime.h>

#define N_NODES 50000
#define E_EDGES 1600000
#define HC 128
#define NEG_SLOPE 0.2f
#define SM_EPS 1e-16f
#define NBKT 782          // ceil(50000/64) coarse buckets (dst>>6)
#define BKT_STRIDE 2600   // slack per bucket (avg 2048, +12 sigma)
#define EPB1 4096         // edges per kc1 block
#define NB1 391           // ceil(1600000/4096)

typedef __attribute__((ext_vector_type(8))) short short8v;
typedef __attribute__((ext_vector_type(4))) float f32x4;

__device__ inline unsigned bf16pack(float a, float b) {
  unsigned ua = __float_as_uint(a), ub = __float_as_uint(b);
  ua = (ua + 0x7fffu + ((ua >> 16) & 1u)) >> 16;
  ub = (ub + 0x7fffu + ((ub >> 16) & 1u)) >> 16;
  return ua | (ub << 16);
}

// ---------------- K0: build wT[144][256] bf16 (W^T with wvec cols); init gcursor --
__global__ __launch_bounds__(256) void k0_init(
    const float* __restrict__ v_mapping,  // [64,256]
    const float* __restrict__ att_src,    // [64]
    const float* __restrict__ att_dst,    // [64]
    const float* __restrict__ W,          // [256,128]
    unsigned short* __restrict__ wT,      // [144,256] bf16
    int* __restrict__ gcursor) {
  const int tid = threadIdx.x, bid = blockIdx.x;
  if (bid == 0)
    for (int i = tid; i < NBKT; i += 256) gcursor[i] = i * BKT_STRIDE;

  __shared__ float wv[2][256];
  {
    const int j = tid;
    float ns = 0.f, nd = 0.f;
    for (int f = 0; f < 64; ++f) {
      float a = att_src[f]; ns = fmaf(a, a, ns);
      float b = att_dst[f]; nd = fmaf(b, b, nd);
    }
    ns = fmaxf(sqrtf(ns), 1e-12f);
    nd = fmaxf(sqrtf(nd), 1e-12f);
    float s = 0.f, d = 0.f;
    for (int f = 0; f < 64; ++f) {
      float v = v_mapping[f * 256 + j];
      s = fmaf(v, att_src[f], s);
      d = fmaf(v, att_dst[f], d);
    }
    wv[0][j] = s / ns;
    wv[1][j] = d / nd;
  }
  __syncthreads();

#pragma unroll
  for (int r = 0; r < 8; ++r) {
    const int n = bid * 8 + r;
    const int k = tid;
    float v;
    if (n < 128) v = W[k * 128 + n];
    else if (n == 128) v = wv[0][k];
    else if (n == 129) v = wv[1][k];
    else v = 0.f;
    unsigned u = __float_as_uint(v);
    u = (u + 0x7fffu + ((u >> 16) & 1u)) >> 16;
    wT[n * 256 + k] = (unsigned short)u;
  }
}

// ---------------- K1: node GEMM via MFMA (bf16), dots folded as cols 128/129 ------
__global__ __launch_bounds__(256) void k1_node(
    const float* __restrict__ x,            // [N,256]
    const unsigned short* __restrict__ wT,  // [144,256] bf16
    unsigned* __restrict__ xpb,             // [N,64] bf16x2 packed
    float* __restrict__ a_src, float* __restrict__ a_dst) {
  __shared__ unsigned short xs[64 * 264];   // bf16, row stride 264 (528B)
  const int tid = threadIdx.x;
  const int w = tid >> 6, lane = tid & 63;
  const int rowbase = blockIdx.x * 64;

  const float4* x4 = (const float4*)x;
#pragma unroll
  for (int c = 0; c < 16; ++c) {
    const int idx = c * 256 + tid;
    const int row = idx >> 6, c4 = idx & 63;
    float4 v = make_float4(0.f, 0.f, 0.f, 0.f);
    if (rowbase + row < N_NODES) v = x4[(size_t)(rowbase + row) * 64 + c4];
    uint2 p;
    p.x = bf16pack(v.x, v.y);
    p.y = bf16pack(v.z, v.w);
    *(uint2*)&xs[row * 264 + c4 * 4] = p;
  }
  __syncthreads();

  f32x4 acc[9];
#pragma unroll
  for (int t = 0; t < 9; ++t) acc[t] = (f32x4){0.f, 0.f, 0.f, 0.f};

  const int m = lane & 15, kq = lane >> 4;
  const unsigned short* arow = &xs[(w * 16 + m) * 264 + kq * 8];
#pragma unroll
  for (int ks = 0; ks < 8; ++ks) {
    const short8v af = *(const short8v*)(arow + ks * 32);
#pragma unroll
    for (int ct = 0; ct < 9; ++ct) {
      const short8v bf = *(const short8v*)(wT + (ct * 16 + m) * 256 + ks * 32 + kq * 8);
      acc[ct] = __builtin_amdgcn_mfma_f32_16x16x32_bf16(af, bf, acc[ct], 0, 0, 0);
    }
  }

  if (m < 2) {
    float* ap = m ? a_dst : a_src;
#pragma unroll
    for (int i = 0; i < 4; ++i) {
      const int rg = rowbase + w * 16 + kq * 4 + i;
      if (rg < N_NODES) ap[rg] = acc[8][i];
    }
  }

  float* cs = (float*)&xs[w * 16 * 264];
#pragma unroll
  for (int ct = 0; ct < 8; ++ct)
#pragma unroll
    for (int i = 0; i < 4; ++i)
      cs[(kq * 4 + i) * 132 + ct * 16 + m] = acc[ct][i];
  __syncthreads();

  const int prow = lane & 15, q = lane >> 4;
  const int grow = rowbase + w * 16 + prow;
  unsigned uu[16];
#pragma unroll
  for (int u = 0; u < 16; ++u) {
    const float2 f2 = *(const float2*)&cs[prow * 132 + q * 32 + u * 2];
    uu[u] = bf16pack(f2.x, f2.y);
  }
  if (grow < N_NODES) {
    uint4* d4 = (uint4*)&xpb[(size_t)grow * 64 + q * 16];
    d4[0] = make_uint4(uu[0], uu[1], uu[2], uu[3]);
    d4[1] = make_uint4(uu[4], uu[5], uu[6], uu[7]);
    d4[2] = make_uint4(uu[8], uu[9], uu[10], uu[11]);
    d4[3] = make_uint4(uu[12], uu[13], uu[14], uu[15]);
  }
}

// ---------------- KC1: coarse bucket scatter, 1024 threads (16 waves/block) -------
__global__ __launch_bounds__(1024) void kc1_coarse(
    const int* __restrict__ ei,
    const float* __restrict__ a_src, const float* __restrict__ a_dst,
    int* __restrict__ gcursor, int2* __restrict__ coarse) {
  __shared__ int chist[NBKT];
  __shared__ int gbase[NBKT];
  __shared__ int ccur[NBKT];
  const int tid = threadIdx.x;
  const int ebase = blockIdx.x * EPB1;
  for (int b = tid; b < NBKT; b += 1024) { chist[b] = 0; ccur[b] = 0; }
  __syncthreads();

  // pass A: LDS histogram (4 edges/thread)
#pragma unroll
  for (int i = 0; i < 4; ++i) {
    const int e = ebase + i * 1024 + tid;
    if (e < E_EDGES) atomicAdd(&chist[ei[E_EDGES + e] >> 6], 1);
  }
  __syncthreads();

  for (int b = tid; b < NBKT; b += 1024) {
    const int c = chist[b];
    if (c > 0) gbase[b] = atomicAdd(&gcursor[b], c);
  }
  __syncthreads();

  // pass B: compute ev, scatter
#pragma unroll
  for (int i = 0; i < 4; ++i) {
    const int e = ebase + i * 1024 + tid;
    if (e < E_EDGES) {
      const int s = ei[e];
      const int d = ei[E_EDGES + e];
      const int b = d >> 6;
      float a = a_src[s] + a_dst[d];
      a = a > 0.f ? a : NEG_SLOPE * a;
      const float ev = __expf(a);
      const int pos = gbase[b] + atomicAdd(&ccur[b], 1);
      if (pos < (b + 1) * BKT_STRIDE)
        coarse[pos] = make_int2(s | ((d & 63) << 16), __float_as_int(ev));
    }
  }
}

// ---------------- KC2: per-bucket LDS counting-sort + gather-reduce, 512 thr ------
__global__ __launch_bounds__(512) void kc2_reduce(
    const int* __restrict__ gcursor, const int2* __restrict__ coarse,
    const unsigned* __restrict__ xpb,   // [N,64] bf16x2
    const float* __restrict__ bias,     // [128]
    float* __restrict__ out) {
  __shared__ unsigned sorted[BKT_STRIDE];  // {src:16 | ev_bf16:16}
  __shared__ int hist[64], cur[64];
  __shared__ int base[65];
  const int b = blockIdx.x;
  const int tid = threadIdx.x;
  const int cstart = b * BKT_STRIDE;
  const int cnt = min(gcursor[b] - cstart, BKT_STRIDE);

  if (tid < 64) { hist[tid] = 0; cur[tid] = 0; }
  __syncthreads();

  for (int j = tid; j < cnt; j += 512)
    atomicAdd(&hist[(coarse[cstart + j].x >> 16) & 63], 1);
  __syncthreads();

  if (tid < 64) {
    const int h = hist[tid];
    int inc = h;
#pragma unroll
    for (int off = 1; off < 64; off <<= 1) {
      int t = __shfl_up(inc, off);
      if (tid >= off) inc += t;
    }
    base[tid] = inc - h;
    if (tid == 63) base[64] = inc;
  }
  __syncthreads();

  for (int j = tid; j < cnt; j += 512) {
    const int2 e2 = coarse[cstart + j];
    const int dloc = (e2.x >> 16) & 63;
    unsigned uev = (unsigned)e2.y;
    uev = (uev + 0x7fffu + ((uev >> 16) & 1u)) >> 16;
    const int p = base[dloc] + atomicAdd(&cur[dloc], 1);
    sorted[p] = (unsigned)(e2.x & 0xffff) | (uev << 16);
  }
  __syncthreads();

  // reduce: 32 groups of 16 lanes; each group handles 2 dsts
  const int g = tid >> 4, gl = tid & 15;
  const uint4* xp4 = (const uint4*)xpb;
  const float4* br = (const float4*)bias;
  const float4 b0 = br[2 * gl], b1 = br[2 * gl + 1];

  for (int dl = g; dl < 64; dl += 32) {
    const int dst = (b << 6) | dl;
    if (dst >= N_NODES) break;
    const int s0 = base[dl];
    const int cntd = base[dl + 1] - s0;

    float acc[8];
#pragma unroll
    for (int i = 0; i < 8; ++i) acc[i] = 0.f;
    float den = 0.f;

    int j = 0;
    for (; j + 2 <= cntd; j += 2) {
      const unsigned uA = sorted[s0 + j];
      const unsigned uB = sorted[s0 + j + 1];
      const float evA = __uint_as_float(uA & 0xffff0000u);
      const float evB = __uint_as_float(uB & 0xffff0000u);
      const uint4 vA = xp4[(size_t)(uA & 0xffffu) * 16 + gl];
      const uint4 vB = xp4[(size_t)(uB & 0xffffu) * 16 + gl];
      den += evA + evB;
      acc[0] = fmaf(evA, __uint_as_float(vA.x << 16), acc[0]);
      acc[1] = fmaf(evA, __uint_as_float(vA.x & 0xffff0000u), acc[1]);
      acc[2] = fmaf(evA, __uint_as_float(vA.y << 16), acc[2]);
      acc[3] = fmaf(evA, __uint_as_float(vA.y & 0xffff0000u), acc[3]);
      acc[4] = fmaf(evA, __uint_as_float(vA.z << 16), acc[4]);
      acc[5] = fmaf(evA, __uint_as_float(vA.z & 0xffff0000u), acc[5]);
      acc[6] = fmaf(evA, __uint_as_float(vA.w << 16), acc[6]);
      acc[7] = fmaf(evA, __uint_as_float(vA.w & 0xffff0000u), acc[7]);
      acc[0] = fmaf(evB, __uint_as_float(vB.x << 16), acc[0]);
      acc[1] = fmaf(evB, __uint_as_float(vB.x & 0xffff0000u), acc[1]);
      acc[2] = fmaf(evB, __uint_as_float(vB.y << 16), acc[2]);
      acc[3] = fmaf(evB, __uint_as_float(vB.y & 0xffff0000u), acc[3]);
      acc[4] = fmaf(evB, __uint_as_float(vB.z << 16), acc[4]);
      acc[5] = fmaf(evB, __uint_as_float(vB.z & 0xffff0000u), acc[5]);
      acc[6] = fmaf(evB, __uint_as_float(vB.w << 16), acc[6]);
      acc[7] = fmaf(evB, __uint_as_float(vB.w & 0xffff0000u), acc[7]);
    }
    if (j < cntd) {
      const unsigned u = sorted[s0 + j];
      const float ev = __uint_as_float(u & 0xffff0000u);
      const uint4 v = xp4[(size_t)(u & 0xffffu) * 16 + gl];
      den += ev;
      acc[0] = fmaf(ev, __uint_as_float(v.x << 16), acc[0]);
      acc[1] = fmaf(ev, __uint_as_float(v.x & 0xffff0000u), acc[1]);
      acc[2] = fmaf(ev, __uint_as_float(v.y << 16), acc[2]);
      acc[3] = fmaf(ev, __uint_as_float(v.y & 0xffff0000u), acc[3]);
      acc[4] = fmaf(ev, __uint_as_float(v.z << 16), acc[4]);
      acc[5] = fmaf(ev, __uint_as_float(v.z & 0xffff0000u), acc[5]);
      acc[6] = fmaf(ev, __uint_as_float(v.w << 16), acc[6]);
      acc[7] = fmaf(ev, __uint_as_float(v.w & 0xffff0000u), acc[7]);
    }

    const float inv = 1.f / (den + SM_EPS);
    const uint4 ur = xp4[(size_t)dst * 16 + gl];
    float4 o0, o1;
    o0.x = __uint_as_float(ur.x << 16)         + b0.x + acc[0] * inv;
    o0.y = __uint_as_float(ur.x & 0xffff0000u) + b0.y + acc[1] * inv;
    o0.z = __uint_as_float(ur.y << 16)         + b0.z + acc[2] * inv;
    o0.w = __uint_as_float(ur.y & 0xffff0000u) + b0.w + acc[3] * inv;
    o1.x = __uint_as_float(ur.z << 16)         + b1.x + acc[4] * inv;
    o1.y = __uint_as_float(ur.z & 0xffff0000u) + b1.y + acc[5] * inv;
    o1.z = __uint_as_float(ur.w << 16)         + b1.z + acc[6] * inv;
    o1.w = __uint_as_float(ur.w & 0xffff0000u) + b1.w + acc[7] * inv;
    float4* orow = (float4*)(out + (size_t)dst * HC);
    orow[2 * gl] = o0;
    orow[2 * gl + 1] = o1;
  }
}

extern "C" void kernel_launch(void* const* d_in, const int* in_sizes, int n_in,
                              void* d_out, int out_size, void* d_ws, size_t ws_size,
                              hipStream_t stream) {
  const float* x         = (const float*)d_in[0];
  const int*   ei        = (const int*)d_in[1];
  const float* v_mapping = (const float*)d_in[2];
  const float* W_src     = (const float*)d_in[3];
  const float* att_src   = (const float*)d_in[4];
  const float* att_dst   = (const float*)d_in[5];
  const float* bias      = (const float*)d_in[6];
  float* out = (float*)d_out;

  char* ws = (char*)d_ws;
  unsigned*       xpb     = (unsigned*)ws;        ws += (size_t)N_NODES * 64 * 4;  // 12.8 MB
  float*          a_src   = (float*)ws;           ws += (size_t)N_NODES * 4;
  float*          a_dst   = (float*)ws;           ws += (size_t)N_NODES * 4;
  unsigned short* wT      = (unsigned short*)ws;  ws += 144 * 256 * 2;             // 73.7 KB
  int*            gcursor = (int*)ws;             ws += ((NBKT + 127) / 128) * 128 * 4;
  int2*           coarse  = (int2*)ws;            ws += (size_t)NBKT * BKT_STRIDE * 8;  // 16.3 MB

  k0_init<<<18, 256, 0, stream>>>(v_mapping, att_src, att_dst, W_src, wT, gcursor);
  k1_node<<<(N_NODES + 63) / 64, 256, 0, stream>>>(x, wT, xpb, a_src, a_dst);
  kc1_coarse<<<NB1, 1024, 0, stream>>>(ei, a_src, a_dst, gcursor, coarse);
  kc2_reduce<<<NBKT, 512, 0, stream>>>(gcursor, coarse, xpb, bias, out);
}